// Round 8
// baseline (9220.510 us; speedup 1.0000x reference)
//
#include <hip/hip_runtime.h>
#include <hip/hip_bf16.h>
#include <math.h>

#define N_NODESC 32768
#define N_EDGESC 524288
#define NPG 8192
#define KOUT 512

typedef unsigned short u16;
typedef unsigned int u32;
typedef unsigned long long u64;

__device__ __forceinline__ float siluf(float x) {
    return x / (1.f + __expf(-x));
}

// ---------------- h0 = x@proj_w + proj_b + sincos(mesh_pos)  (+ zero deg) ----------------
__global__ __launch_bounds__(256) void k_h0(const float* __restrict__ x,
                                            const float* __restrict__ pos,
                                            const float* __restrict__ pw,
                                            const float* __restrict__ pb,
                                            float* __restrict__ h,
                                            int* __restrict__ deg) {
    int gid = blockIdx.x * 256 + threadIdx.x;
    if (gid < N_NODESC) deg[gid] = 0;
    int node = blockIdx.x * 2 + (threadIdx.x >> 7);
    int c = threadIdx.x & 127;
    float x0 = x[node * 3 + 0];
    float x1 = x[node * 3 + 1];
    float x2 = x[node * 3 + 2];
    float acc = x0 * pw[c] + x1 * pw[128 + c] + x2 * pw[256 + c];
    acc += pb[c];
    int dim = c >> 6;
    int inner = c & 63;
    int jj = inner & 31;
    float p = pos[node * 2 + dim];
    float omega = exp2f(-(float)jj * 0.41524101186092027f);
    float ang = p * omega;
    acc += (inner < 32) ? __sinf(ang) : __cosf(ang);
    h[(size_t)node * 128 + c] = acc;
}

// ---------------- degree histogram ----------------
__global__ __launch_bounds__(256) void k_deg(const int* __restrict__ edges, int* __restrict__ deg) {
    int e = blockIdx.x * 256 + threadIdx.x;
    if (e < N_EDGESC) {
        int2 e2 = ((const int2*)edges)[e];
        atomicAdd(&deg[e2.y], 1);
    }
}

// ---------------- exclusive scan (32768 = 1024 threads x 32) ----------------
__global__ __launch_bounds__(1024) void k_scan(const int* __restrict__ deg,
                                               int* __restrict__ off, int* __restrict__ cur,
                                               float* __restrict__ rs, float* __restrict__ bg) {
    __shared__ int ls[1024];
    int tid = threadIdx.x;
    int base = tid * 32;
    int v[32];
    int s = 0;
#pragma unroll
    for (int j = 0; j < 32; j++) { v[j] = deg[base + j]; s += v[j]; }
    ls[tid] = s;
    __syncthreads();
    for (int ofs = 1; ofs < 1024; ofs <<= 1) {
        int t = (tid >= ofs) ? ls[tid - ofs] : 0;
        __syncthreads();
        ls[tid] += t;
        __syncthreads();
    }
    int run = ls[tid] - s;
#pragma unroll
    for (int j = 0; j < 32; j++) {
        off[base + j] = run;
        cur[base + j] = run;
        int d = v[j];
        rs[base + j] = 1.f / (float)(d > 0 ? d : 1);
        bg[base + j] = d > 0 ? 1.f : 0.f;
        run += d;
    }
}

// ---------------- CSR fill ----------------
__global__ __launch_bounds__(256) void k_fill(const int* __restrict__ edges,
                                              int* __restrict__ cur, int* __restrict__ csr) {
    int e = blockIdx.x * 256 + threadIdx.x;
    if (e < N_EDGESC) {
        int2 e2 = ((const int2*)edges)[e];
        int pos = atomicAdd(&cur[e2.y], 1);
        csr[pos] = e2.x;
    }
}

// ---------------- pipelined f32 GEMM, templated ----------------
// acc1 = A1@W1 ; acc2 = (HASA2 ? A2 : A1) @ W2   (W2 path active iff HASA2||DUALOUT)
// DUALOUT: C = acc1 ; C2 = acc2 + bias1
// else:    C = act( (acc1+acc2)*rs + bias1*bg + resid ), fused wrel/wroot dots
template <bool HASA2, bool DUALOUT>
__global__ __launch_bounds__(256, 2) void gemm_t(const float* __restrict__ A1, const float* __restrict__ W1,
                                                 const float* __restrict__ A2, const float* __restrict__ W2,
                                                 const float* __restrict__ bias1,
                                                 const float* __restrict__ rs, const float* __restrict__ bg,
                                                 const float* __restrict__ resid,
                                                 float* __restrict__ C, float* __restrict__ C2, int act,
                                                 const float* __restrict__ wrel, const float* __restrict__ wroot,
                                                 float* __restrict__ pout, float* __restrict__ rout) {
    constexpr bool USEW2 = HASA2 || DUALOUT;
    int cg = threadIdx.x & 31;
    int rg = threadIdx.x >> 5;
    int m0 = blockIdx.x * 32 + rg * 4;
    int c0 = cg * 4;

    const float* Ar1 = A1 + (size_t)m0 * 128;
    const float* Ar2 = HASA2 ? (A2 + (size_t)m0 * 128) : nullptr;

    float acc1[4][4], acc2[4][4];
#pragma unroll
    for (int r = 0; r < 4; r++)
#pragma unroll
        for (int c = 0; c < 4; c++) { acc1[r][c] = 0.f; acc2[r][c] = 0.f; }

    float4 a1b[2][4], w1b[2][4], a2b[2][4], w2b[2][4];

    // preload k0 = 0
#pragma unroll
    for (int r = 0; r < 4; r++) a1b[0][r] = *(const float4*)(Ar1 + r * 128);
#pragma unroll
    for (int kk = 0; kk < 4; kk++) w1b[0][kk] = *(const float4*)(W1 + (size_t)kk * 128 + c0);
    if (HASA2) {
#pragma unroll
        for (int r = 0; r < 4; r++) a2b[0][r] = *(const float4*)(Ar2 + r * 128);
    }
    if (USEW2) {
#pragma unroll
        for (int kk = 0; kk < 4; kk++) w2b[0][kk] = *(const float4*)(W2 + (size_t)kk * 128 + c0);
    }

#pragma unroll
    for (int k0 = 0; k0 < 128; k0 += 4) {
        const int cur = (k0 >> 2) & 1, nxt = cur ^ 1;
        if (k0 < 124) {
            int kn = k0 + 4;
#pragma unroll
            for (int r = 0; r < 4; r++) a1b[nxt][r] = *(const float4*)(Ar1 + r * 128 + kn);
#pragma unroll
            for (int kk = 0; kk < 4; kk++) w1b[nxt][kk] = *(const float4*)(W1 + (size_t)(kn + kk) * 128 + c0);
            if (HASA2) {
#pragma unroll
                for (int r = 0; r < 4; r++) a2b[nxt][r] = *(const float4*)(Ar2 + r * 128 + kn);
            }
            if (USEW2) {
#pragma unroll
                for (int kk = 0; kk < 4; kk++) w2b[nxt][kk] = *(const float4*)(W2 + (size_t)(kn + kk) * 128 + c0);
            }
        }
#pragma unroll
        for (int kk = 0; kk < 4; kk++) {
            float4 w1 = w1b[cur][kk];
#pragma unroll
            for (int r = 0; r < 4; r++) {
                float a = ((const float*)&a1b[cur][r])[kk];
                acc1[r][0] += a * w1.x;
                acc1[r][1] += a * w1.y;
                acc1[r][2] += a * w1.z;
                acc1[r][3] += a * w1.w;
            }
            if (USEW2) {
                float4 w2 = w2b[cur][kk];
#pragma unroll
                for (int r = 0; r < 4; r++) {
                    float a = HASA2 ? ((const float*)&a2b[cur][r])[kk]
                                    : ((const float*)&a1b[cur][r])[kk];
                    acc2[r][0] += a * w2.x;
                    acc2[r][1] += a * w2.y;
                    acc2[r][2] += a * w2.z;
                    acc2[r][3] += a * w2.w;
                }
            }
        }
    }

    if (DUALOUT) {
#pragma unroll
        for (int r = 0; r < 4; r++) {
            int row = m0 + r;
            float4 o1, o2;
            o1.x = acc1[r][0]; o1.y = acc1[r][1]; o1.z = acc1[r][2]; o1.w = acc1[r][3];
            o2.x = acc2[r][0] + bias1[c0];
            o2.y = acc2[r][1] + bias1[c0 + 1];
            o2.z = acc2[r][2] + bias1[c0 + 2];
            o2.w = acc2[r][3] + bias1[c0 + 3];
            *(float4*)(C + (size_t)row * 128 + c0) = o1;
            *(float4*)(C2 + (size_t)row * 128 + c0) = o2;
        }
    } else {
        float prel[4], prot[4];
#pragma unroll
        for (int r = 0; r < 4; r++) {
            int row = m0 + r;
            float rsv = rs ? rs[row] : 1.f;
            float bgv = bg ? bg[row] : 1.f;
            float4 o;
            float* op = (float*)&o;
#pragma unroll
            for (int c = 0; c < 4; c++) {
                float xv = acc1[r][c];
                if (HASA2) xv += acc2[r][c];
                xv *= rsv;
                if (bias1) xv += bias1[c0 + c] * bgv;
                if (resid) xv += resid[(size_t)row * 128 + c0 + c];
                if (act) xv = siluf(xv);
                op[c] = xv;
            }
            if (wrel) {
                prel[r] = op[0] * wrel[c0] + op[1] * wrel[c0 + 1] + op[2] * wrel[c0 + 2] + op[3] * wrel[c0 + 3];
                prot[r] = op[0] * wroot[c0] + op[1] * wroot[c0 + 1] + op[2] * wroot[c0 + 2] + op[3] * wroot[c0 + 3];
            }
            *(float4*)(C + (size_t)row * 128 + c0) = o;
        }
        if (wrel) {
#pragma unroll
            for (int r = 0; r < 4; r++) {
                float a = prel[r], b = prot[r];
#pragma unroll
                for (int m = 1; m < 32; m <<= 1) {
                    a += __shfl_xor(a, m);
                    b += __shfl_xor(b, m);
                }
                if (cg == 0) { pout[m0 + r] = a; rout[m0 + r] = b; }
            }
        }
    }
}

// ---------------- S[d] = sum_{e:dst=d} silu(u[d] + v[src_e]) ; wave per node ----------------
__global__ __launch_bounds__(256) void k_accum_S(const float* __restrict__ v,
                                                 const int* __restrict__ csr, const int* __restrict__ off,
                                                 const int* __restrict__ deg, float* S) {
    int d = blockIdx.x * 4 + (threadIdx.x >> 6);
    int lane = threadIdx.x & 63;
    float* srow = S + (size_t)d * 128;
    float u0 = srow[lane];
    float u1 = srow[64 + lane];
    float a0 = 0.f, a1 = 0.f;
    int o = off[d], n = deg[d];
    for (int base = 0; base < n; base += 64) {
        int cnt = min(64, n - base);
        int sall = (lane < cnt) ? csr[o + base + lane] : 0;
        int s0 = __shfl(sall, 0);
        float p00 = v[(size_t)s0 * 128 + lane];
        float p01 = v[(size_t)s0 * 128 + 64 + lane];
        float p10 = 0.f, p11 = 0.f;
        if (cnt > 1) {
            int s1 = __shfl(sall, 1);
            p10 = v[(size_t)s1 * 128 + lane];
            p11 = v[(size_t)s1 * 128 + 64 + lane];
        }
        for (int j = 0; j < cnt; j++) {
            float cv0 = p00, cv1 = p01;
            p00 = p10; p01 = p11;
            if (j + 2 < cnt) {
                int sn = __shfl(sall, j + 2);
                p10 = v[(size_t)sn * 128 + lane];
                p11 = v[(size_t)sn * 128 + 64 + lane];
            }
            a0 += siluf(u0 + cv0);
            a1 += siluf(u1 + cv1);
        }
    }
    srow[lane] = a0;
    srow[64 + lane] = a1;
}

// ---------------- score[d] = tanh( (sum p[src]) / cnt + rel_b + r[d] ) ----------------
__global__ __launch_bounds__(256) void k_score(const float* __restrict__ p, const float* __restrict__ r,
                                               const int* __restrict__ csr, const int* __restrict__ off,
                                               const int* __restrict__ deg, const float* __restrict__ relb,
                                               float* __restrict__ score) {
    int d = blockIdx.x * 4 + (threadIdx.x >> 6);
    int lane = threadIdx.x & 63;
    int o = off[d], n = deg[d];
    float a = 0.f;
    for (int j = lane; j < n; j += 64) a += p[csr[o + j]];
    for (int m = 32; m > 0; m >>= 1) a += __shfl_xor(a, m);
    if (lane == 0) {
        float cnt = (float)(n > 0 ? n : 1);
        score[d] = tanhf(a / cnt + relb[0] + r[d]);
    }
}

// ---------------- per-graph exact top-k via radix-select + direct ranking ----------------
__global__ __launch_bounds__(1024) void k_topk(const float* __restrict__ score, const float* __restrict__ h,
                                               float* __restrict__ out) {
    __shared__ u32 ms[NPG];
    __shared__ u32 hist[256];
    __shared__ u32 sbuf[1024];
    __shared__ u64 sel[KOUT];
    __shared__ float ordv[KOUT];
    __shared__ int ordi[KOUT];
    __shared__ u32 selCnt, sPrefix, sNeed, sB;

    int g = blockIdx.x;
    int tid = threadIdx.x;

    for (int i = tid; i < NPG; i += 1024) {
        u32 u = __float_as_uint(score[(size_t)g * NPG + i]);
        ms[i] = (u & 0x80000000u) ? ~u : (u | 0x80000000u);
    }
    if (tid == 0) { sNeed = KOUT; sPrefix = 0; selCnt = 0; }
    __syncthreads();

    for (int pass = 0; pass < 4; pass++) {
        int shift = 24 - pass * 8;
        if (tid < 256) hist[tid] = 0;
        __syncthreads();
        u32 pfx = sPrefix;
        for (int i = tid; i < NPG; i += 1024) {
            u32 v = ms[i];
            if (pass == 0 || (v >> (shift + 8)) == pfx)
                atomicAdd(&hist[(v >> shift) & 255u], 1u);
        }
        __syncthreads();
        if (tid < 256) sbuf[tid] = hist[tid];
        __syncthreads();
        for (int ofs = 1; ofs < 256; ofs <<= 1) {
            u32 t = 0;
            if (tid < 256 && tid + ofs < 256) t = sbuf[tid + ofs];
            __syncthreads();
            if (tid < 256) sbuf[tid] += t;
            __syncthreads();
        }
        u32 need = sNeed;
        if (tid < 256) {
            if (sbuf[tid] >= need && (tid == 255 || sbuf[tid + 1] < need)) sB = (u32)tid;
        }
        __syncthreads();
        if (tid == 0) {
            u32 B = sB;
            u32 above = (B == 255) ? 0u : sbuf[B + 1];
            sNeed = need - above;
            sPrefix = (sPrefix << 8) | B;
        }
        __syncthreads();
    }
    u32 T = sPrefix;
    u32 rTie = sNeed;

    int base = tid * 8;
    u32 lc = 0;
#pragma unroll
    for (int j = 0; j < 8; j++) lc += (ms[base + j] == T);
    __syncthreads();
    sbuf[tid] = lc;
    __syncthreads();
    u32 own = lc;
    for (int ofs = 1; ofs < 1024; ofs <<= 1) {
        u32 t = (tid >= ofs) ? sbuf[tid - ofs] : 0;
        __syncthreads();
        sbuf[tid] += t;
        __syncthreads();
    }
    u32 excl = sbuf[tid] - own;

#pragma unroll
    for (int j = 0; j < 8; j++) {
        int i = base + j;
        u32 v = ms[i];
        bool pick = (v > T) || ((v == T) && (excl < rTie));
        if (v == T) excl++;
        if (pick) {
            u32 slot = atomicAdd(&selCnt, 1u);
            sel[slot] = ((u64)v << 32) | (u32)(NPG - 1 - i);
        }
    }
    __syncthreads();

    if (tid < KOUT) {
        u64 mine = sel[tid];
        int rank = 0;
        for (int j = 0; j < KOUT; j++) rank += (sel[j] > mine);
        u32 v = (u32)(mine >> 32);
        int idx = NPG - 1 - (int)(mine & 0xFFFFFFFFu);
        u32 uu = (v & 0x80000000u) ? (v & 0x7FFFFFFFu) : ~v;
        ordv[rank] = __uint_as_float(uu);
        ordi[rank] = idx;
    }
    __syncthreads();

    for (int t = tid; t < KOUT * 128; t += 1024) {
        int r = t >> 7, c = t & 127;
        int node = g * NPG + ordi[r];
        out[((size_t)g * KOUT + r) * 128 + c] = h[(size_t)node * 128 + c] * ordv[r];
    }
    for (int t = tid; t < KOUT; t += 1024)
        out[(size_t)4 * KOUT * 128 + (size_t)g * KOUT + t] = (float)g;
}

extern "C" void kernel_launch(void* const* d_in, const int* in_sizes, int n_in,
                              void* d_out, int out_size, void* d_ws, size_t ws_size,
                              hipStream_t stream) {
    const float* x        = (const float*)d_in[0];
    const float* mesh_pos = (const float*)d_in[1];
    const int*   edges    = (const int*)d_in[2];
    const float* proj_w   = (const float*)d_in[4];
    const float* proj_b   = (const float*)d_in[5];
    const float* msg_w1   = (const float*)d_in[6];
    const float* msg_b1   = (const float*)d_in[7];
    const float* msg_w2   = (const float*)d_in[8];
    const float* msg_b2   = (const float*)d_in[9];
    const float* upd_w1   = (const float*)d_in[10];
    const float* upd_b1   = (const float*)d_in[11];
    const float* upd_w2   = (const float*)d_in[12];
    const float* upd_b2   = (const float*)d_in[13];
    const float* pool_rel_w  = (const float*)d_in[14];
    const float* pool_rel_b  = (const float*)d_in[15];
    const float* pool_root_w = (const float*)d_in[16];
    float* out = (float*)d_out;

    // workspace: 3 x 16MB node buffers + small arrays (~51.1MB)
    char* w = (char*)d_ws;
    float* h  = (float*)(w);                   // h0 -> h_new (in place)
    float* v  = (float*)(w + (1ull << 24));    // v -> agg
    float* S  = (float*)(w + (2ull << 24));    // u -> S -> q
    char* sm  = w + (3ull << 24);
    int*   deg   = (int*)(sm);
    int*   off   = (int*)(sm + 131072);
    int*   cur   = (int*)(sm + 262144);
    float* rsA   = (float*)(sm + 393216);
    float* bgA   = (float*)(sm + 524288);
    float* pp    = (float*)(sm + 655360);
    float* rr    = (float*)(sm + 786432);
    float* score = (float*)(sm + 917504);
    int*   csr   = (int*)(sm + 1048576);       // 2MB

    k_h0<<<N_NODESC / 2, 256, 0, stream>>>(x, mesh_pos, proj_w, proj_b, h, deg);
    k_deg<<<N_EDGESC / 256, 256, 0, stream>>>(edges, deg);
    k_scan<<<1, 1024, 0, stream>>>(deg, off, cur, rsA, bgA);
    k_fill<<<N_EDGESC / 256, 256, 0, stream>>>(edges, cur, csr);

    // v = h@W1b ; S = h@W1a + b1   (one pass over h, dual out)
    gemm_t<false, true><<<1024, 256, 0, stream>>>(h, msg_w1 + 128 * 128, nullptr, msg_w1,
                                                  msg_b1, nullptr, nullptr, nullptr,
                                                  v, S, 0, nullptr, nullptr, nullptr, nullptr);
    // S[d] = sum_e silu( S[d] + v[src_e] )   (in place)
    k_accum_S<<<N_NODESC / 4, 256, 0, stream>>>(v, csr, off, deg, S);
    // agg = (S@W2)*rs + b2*bg   (into v; v dead after accum) — explicit, no pre-multiply
    gemm_t<false, false><<<1024, 256, 0, stream>>>(S, msg_w2, nullptr, nullptr,
                                                   msg_b2, rsA, bgA, nullptr,
                                                   v, nullptr, 0, nullptr, nullptr, nullptr, nullptr);
    // q = silu( h@U1a + agg@U1b + ub1 )  (into S; S dead after agg gemm)
    gemm_t<true, false><<<1024, 256, 0, stream>>>(h, upd_w1, v, upd_w1 + 128 * 128,
                                                  upd_b1, nullptr, nullptr, nullptr,
                                                  S, nullptr, 1, nullptr, nullptr, nullptr, nullptr);
    // h = h + q@U2 + ub2  (in place) + fused p,r dots
    gemm_t<false, false><<<1024, 256, 0, stream>>>(S, upd_w2, nullptr, nullptr,
                                                   upd_b2, nullptr, nullptr, h,
                                                   h, nullptr, 0, pool_rel_w, pool_root_w, pp, rr);

    k_score<<<N_NODESC / 4, 256, 0, stream>>>(pp, rr, csr, off, deg, pool_rel_b, score);
    k_topk<<<4, 1024, 0, stream>>>(score, h, out);
}

// Round 9
// 452.024 us; speedup vs baseline: 20.3983x; 20.3983x over previous
//
#include <hip/hip_runtime.h>
#include <hip/hip_bf16.h>
#include <math.h>

#define N_NODESC 32768
#define N_EDGESC 524288
#define NPG 8192
#define KOUT 512

typedef unsigned short u16;
typedef unsigned int u32;
typedef unsigned long long u64;

__device__ __forceinline__ float siluf(float x) {
    return x / (1.f + __expf(-x));
}

// ---------------- h0 = x@proj_w + proj_b + sincos(mesh_pos)  (+ zero deg) ----------------
__global__ __launch_bounds__(256) void k_h0(const float* __restrict__ x,
                                            const float* __restrict__ pos,
                                            const float* __restrict__ pw,
                                            const float* __restrict__ pb,
                                            float* __restrict__ h,
                                            int* __restrict__ deg) {
    int gid = blockIdx.x * 256 + threadIdx.x;
    if (gid < N_NODESC) deg[gid] = 0;
    int node = blockIdx.x * 2 + (threadIdx.x >> 7);
    int c = threadIdx.x & 127;
    float x0 = x[node * 3 + 0];
    float x1 = x[node * 3 + 1];
    float x2 = x[node * 3 + 2];
    float acc = x0 * pw[c] + x1 * pw[128 + c] + x2 * pw[256 + c];
    acc += pb[c];
    int dim = c >> 6;
    int inner = c & 63;
    int jj = inner & 31;
    float p = pos[node * 2 + dim];
    float omega = exp2f(-(float)jj * 0.41524101186092027f);
    float ang = p * omega;
    acc += (inner < 32) ? __sinf(ang) : __cosf(ang);
    h[(size_t)node * 128 + c] = acc;
}

// ---------------- degree histogram ----------------
__global__ __launch_bounds__(256) void k_deg(const int* __restrict__ edges, int* __restrict__ deg) {
    int e = blockIdx.x * 256 + threadIdx.x;
    if (e < N_EDGESC) {
        int2 e2 = ((const int2*)edges)[e];
        atomicAdd(&deg[e2.y], 1);
    }
}

// ---------------- exclusive scan (32768 = 1024 threads x 32) ----------------
__global__ __launch_bounds__(1024) void k_scan(const int* __restrict__ deg,
                                               int* __restrict__ off, int* __restrict__ cur,
                                               float* __restrict__ rs, float* __restrict__ bg) {
    __shared__ int ls[1024];
    int tid = threadIdx.x;
    int base = tid * 32;
    int v[32];
    int s = 0;
#pragma unroll
    for (int j = 0; j < 32; j++) { v[j] = deg[base + j]; s += v[j]; }
    ls[tid] = s;
    __syncthreads();
    for (int ofs = 1; ofs < 1024; ofs <<= 1) {
        int t = (tid >= ofs) ? ls[tid - ofs] : 0;
        __syncthreads();
        ls[tid] += t;
        __syncthreads();
    }
    int run = ls[tid] - s;
#pragma unroll
    for (int j = 0; j < 32; j++) {
        off[base + j] = run;
        cur[base + j] = run;
        int d = v[j];
        rs[base + j] = 1.f / (float)(d > 0 ? d : 1);
        bg[base + j] = d > 0 ? 1.f : 0.f;
        run += d;
    }
}

// ---------------- CSR fill ----------------
__global__ __launch_bounds__(256) void k_fill(const int* __restrict__ edges,
                                              int* __restrict__ cur, int* __restrict__ csr) {
    int e = blockIdx.x * 256 + threadIdx.x;
    if (e < N_EDGESC) {
        int2 e2 = ((const int2*)edges)[e];
        int pos = atomicAdd(&cur[e2.y], 1);
        csr[pos] = e2.x;
    }
}

// ---------------- pipelined f32 GEMM, templated; named ping-pong buffers ----------------
// acc1 = A1@W1 ; acc2 = (HASA2 ? A2 : A1) @ W2   (W2 path active iff HASA2||DUALOUT)
// DUALOUT: C = acc1 ; C2 = acc2 + bias1
// else:    C = act( (acc1+acc2)*rs + bias1*bg + resid ), fused wrel/wroot dots
template <bool HASA2, bool DUALOUT>
__global__ __launch_bounds__(256, 2) void gemm_t(const float* __restrict__ A1, const float* __restrict__ W1,
                                                 const float* __restrict__ A2, const float* __restrict__ W2,
                                                 const float* __restrict__ bias1,
                                                 const float* __restrict__ rs, const float* __restrict__ bg,
                                                 const float* __restrict__ resid,
                                                 float* __restrict__ C, float* __restrict__ C2, int act,
                                                 const float* __restrict__ wrel, const float* __restrict__ wroot,
                                                 float* __restrict__ pout, float* __restrict__ rout) {
    constexpr bool USEW2 = HASA2 || DUALOUT;
    int cg = threadIdx.x & 31;
    int rg = threadIdx.x >> 5;
    int m0 = blockIdx.x * 32 + rg * 4;
    int c0 = cg * 4;

    const float* Ar1 = A1 + (size_t)m0 * 128;
    const float* Ar2 = HASA2 ? (A2 + (size_t)m0 * 128) : nullptr;

    float acc1[4][4], acc2[4][4];
#pragma unroll
    for (int r = 0; r < 4; r++)
#pragma unroll
        for (int c = 0; c < 4; c++) { acc1[r][c] = 0.f; acc2[r][c] = 0.f; }

    // named ping-pong buffers — every index below is a compile-time literal,
    // so all buffers live in VGPRs (the round-8 [cur][..] form spilled to scratch)
    float4 aA[4], wA[4], a2A[4], w2A[4];
    float4 aB[4], wB[4], a2B[4], w2B[4];

#define LOAD_A(buf, abase, k)                                                    \
    {                                                                            \
        _Pragma("unroll") for (int r = 0; r < 4; r++)                            \
            buf[r] = *(const float4*)((abase) + r * 128 + (k));                  \
    }
#define LOAD_W(buf, wbase, k)                                                    \
    {                                                                            \
        _Pragma("unroll") for (int kk = 0; kk < 4; kk++)                         \
            buf[kk] = *(const float4*)((wbase) + (size_t)((k) + kk) * 128 + c0); \
    }
#define COMPUTE(ab, wb, a2bv, w2bv)                                              \
    {                                                                            \
        _Pragma("unroll") for (int kk = 0; kk < 4; kk++) {                       \
            float4 w1v = wb[kk];                                                 \
            _Pragma("unroll") for (int r = 0; r < 4; r++) {                      \
                float a = ((const float*)&ab[r])[kk];                            \
                acc1[r][0] += a * w1v.x;                                         \
                acc1[r][1] += a * w1v.y;                                         \
                acc1[r][2] += a * w1v.z;                                         \
                acc1[r][3] += a * w1v.w;                                         \
            }                                                                    \
            if (USEW2) {                                                         \
                float4 w2v = w2bv[kk];                                           \
                _Pragma("unroll") for (int r = 0; r < 4; r++) {                  \
                    float a = HASA2 ? ((const float*)&a2bv[r])[kk]               \
                                    : ((const float*)&ab[r])[kk];                \
                    acc2[r][0] += a * w2v.x;                                     \
                    acc2[r][1] += a * w2v.y;                                     \
                    acc2[r][2] += a * w2v.z;                                     \
                    acc2[r][3] += a * w2v.w;                                     \
                }                                                                \
            }                                                                    \
        }                                                                        \
    }

    // preload k=0 into buffer A
    LOAD_A(aA, Ar1, 0)
    LOAD_W(wA, W1, 0)
    if (HASA2) LOAD_A(a2A, Ar2, 0)
    if (USEW2) LOAD_W(w2A, W2, 0)

    for (int k0 = 0; k0 < 128; k0 += 8) {
        // prefetch k0+4 into B while computing A(k0)
        LOAD_A(aB, Ar1, k0 + 4)
        LOAD_W(wB, W1, k0 + 4)
        if (HASA2) LOAD_A(a2B, Ar2, k0 + 4)
        if (USEW2) LOAD_W(w2B, W2, k0 + 4)
        COMPUTE(aA, wA, a2A, w2A)
        // prefetch k0+8 into A while computing B(k0+4)
        if (k0 + 8 < 128) {
            LOAD_A(aA, Ar1, k0 + 8)
            LOAD_W(wA, W1, k0 + 8)
            if (HASA2) LOAD_A(a2A, Ar2, k0 + 8)
            if (USEW2) LOAD_W(w2A, W2, k0 + 8)
        }
        COMPUTE(aB, wB, a2B, w2B)
    }
#undef LOAD_A
#undef LOAD_W
#undef COMPUTE

    if (DUALOUT) {
#pragma unroll
        for (int r = 0; r < 4; r++) {
            int row = m0 + r;
            float4 o1, o2;
            o1.x = acc1[r][0]; o1.y = acc1[r][1]; o1.z = acc1[r][2]; o1.w = acc1[r][3];
            o2.x = acc2[r][0] + bias1[c0];
            o2.y = acc2[r][1] + bias1[c0 + 1];
            o2.z = acc2[r][2] + bias1[c0 + 2];
            o2.w = acc2[r][3] + bias1[c0 + 3];
            *(float4*)(C + (size_t)row * 128 + c0) = o1;
            *(float4*)(C2 + (size_t)row * 128 + c0) = o2;
        }
    } else {
        float prel[4], prot[4];
#pragma unroll
        for (int r = 0; r < 4; r++) {
            int row = m0 + r;
            float rsv = rs ? rs[row] : 1.f;
            float bgv = bg ? bg[row] : 1.f;
            float4 o;
            float* op = (float*)&o;
#pragma unroll
            for (int c = 0; c < 4; c++) {
                float xv = acc1[r][c];
                if (HASA2) xv += acc2[r][c];
                xv *= rsv;
                if (bias1) xv += bias1[c0 + c] * bgv;
                if (resid) xv += resid[(size_t)row * 128 + c0 + c];
                if (act) xv = siluf(xv);
                op[c] = xv;
            }
            if (wrel) {
                prel[r] = op[0] * wrel[c0] + op[1] * wrel[c0 + 1] + op[2] * wrel[c0 + 2] + op[3] * wrel[c0 + 3];
                prot[r] = op[0] * wroot[c0] + op[1] * wroot[c0 + 1] + op[2] * wroot[c0 + 2] + op[3] * wroot[c0 + 3];
            }
            *(float4*)(C + (size_t)row * 128 + c0) = o;
        }
        if (wrel) {
#pragma unroll
            for (int r = 0; r < 4; r++) {
                float a = prel[r], b = prot[r];
#pragma unroll
                for (int m = 1; m < 32; m <<= 1) {
                    a += __shfl_xor(a, m);
                    b += __shfl_xor(b, m);
                }
                if (cg == 0) { pout[m0 + r] = a; rout[m0 + r] = b; }
            }
        }
    }
}

// ---------------- S[d] = sum_{e:dst=d} silu(u[d] + v[src_e]) ; wave per node ----------------
__global__ __launch_bounds__(256) void k_accum_S(const float* __restrict__ v,
                                                 const int* __restrict__ csr, const int* __restrict__ off,
                                                 const int* __restrict__ deg, float* S) {
    int d = blockIdx.x * 4 + (threadIdx.x >> 6);
    int lane = threadIdx.x & 63;
    float* srow = S + (size_t)d * 128;
    float u0 = srow[lane];
    float u1 = srow[64 + lane];
    float a0 = 0.f, a1 = 0.f;
    int o = off[d], n = deg[d];
    for (int base = 0; base < n; base += 64) {
        int cnt = min(64, n - base);
        int sall = (lane < cnt) ? csr[o + base + lane] : 0;
        int s0 = __shfl(sall, 0);
        float p00 = v[(size_t)s0 * 128 + lane];
        float p01 = v[(size_t)s0 * 128 + 64 + lane];
        float p10 = 0.f, p11 = 0.f;
        if (cnt > 1) {
            int s1 = __shfl(sall, 1);
            p10 = v[(size_t)s1 * 128 + lane];
            p11 = v[(size_t)s1 * 128 + 64 + lane];
        }
        for (int j = 0; j < cnt; j++) {
            float cv0 = p00, cv1 = p01;
            p00 = p10; p01 = p11;
            if (j + 2 < cnt) {
                int sn = __shfl(sall, j + 2);
                p10 = v[(size_t)sn * 128 + lane];
                p11 = v[(size_t)sn * 128 + 64 + lane];
            }
            a0 += siluf(u0 + cv0);
            a1 += siluf(u1 + cv1);
        }
    }
    srow[lane] = a0;
    srow[64 + lane] = a1;
}

// ---------------- score[d] = tanh( (sum p[src]) / cnt + rel_b + r[d] ) ----------------
__global__ __launch_bounds__(256) void k_score(const float* __restrict__ p, const float* __restrict__ r,
                                               const int* __restrict__ csr, const int* __restrict__ off,
                                               const int* __restrict__ deg, const float* __restrict__ relb,
                                               float* __restrict__ score) {
    int d = blockIdx.x * 4 + (threadIdx.x >> 6);
    int lane = threadIdx.x & 63;
    int o = off[d], n = deg[d];
    float a = 0.f;
    for (int j = lane; j < n; j += 64) a += p[csr[o + j]];
    for (int m = 32; m > 0; m >>= 1) a += __shfl_xor(a, m);
    if (lane == 0) {
        float cnt = (float)(n > 0 ? n : 1);
        score[d] = tanhf(a / cnt + relb[0] + r[d]);
    }
}

// ---------------- per-graph exact top-k via radix-select + direct ranking ----------------
__global__ __launch_bounds__(1024) void k_topk(const float* __restrict__ score, const float* __restrict__ h,
                                               float* __restrict__ out) {
    __shared__ u32 ms[NPG];
    __shared__ u32 hist[256];
    __shared__ u32 sbuf[1024];
    __shared__ u64 sel[KOUT];
    __shared__ float ordv[KOUT];
    __shared__ int ordi[KOUT];
    __shared__ u32 selCnt, sPrefix, sNeed, sB;

    int g = blockIdx.x;
    int tid = threadIdx.x;

    for (int i = tid; i < NPG; i += 1024) {
        u32 u = __float_as_uint(score[(size_t)g * NPG + i]);
        ms[i] = (u & 0x80000000u) ? ~u : (u | 0x80000000u);
    }
    if (tid == 0) { sNeed = KOUT; sPrefix = 0; selCnt = 0; }
    __syncthreads();

    for (int pass = 0; pass < 4; pass++) {
        int shift = 24 - pass * 8;
        if (tid < 256) hist[tid] = 0;
        __syncthreads();
        u32 pfx = sPrefix;
        for (int i = tid; i < NPG; i += 1024) {
            u32 v = ms[i];
            if (pass == 0 || (v >> (shift + 8)) == pfx)
                atomicAdd(&hist[(v >> shift) & 255u], 1u);
        }
        __syncthreads();
        if (tid < 256) sbuf[tid] = hist[tid];
        __syncthreads();
        for (int ofs = 1; ofs < 256; ofs <<= 1) {
            u32 t = 0;
            if (tid < 256 && tid + ofs < 256) t = sbuf[tid + ofs];
            __syncthreads();
            if (tid < 256) sbuf[tid] += t;
            __syncthreads();
        }
        u32 need = sNeed;
        if (tid < 256) {
            if (sbuf[tid] >= need && (tid == 255 || sbuf[tid + 1] < need)) sB = (u32)tid;
        }
        __syncthreads();
        if (tid == 0) {
            u32 B = sB;
            u32 above = (B == 255) ? 0u : sbuf[B + 1];
            sNeed = need - above;
            sPrefix = (sPrefix << 8) | B;
        }
        __syncthreads();
    }
    u32 T = sPrefix;
    u32 rTie = sNeed;

    int base = tid * 8;
    u32 lc = 0;
#pragma unroll
    for (int j = 0; j < 8; j++) lc += (ms[base + j] == T);
    __syncthreads();
    sbuf[tid] = lc;
    __syncthreads();
    u32 own = lc;
    for (int ofs = 1; ofs < 1024; ofs <<= 1) {
        u32 t = (tid >= ofs) ? sbuf[tid - ofs] : 0;
        __syncthreads();
        sbuf[tid] += t;
        __syncthreads();
    }
    u32 excl = sbuf[tid] - own;

#pragma unroll
    for (int j = 0; j < 8; j++) {
        int i = base + j;
        u32 v = ms[i];
        bool pick = (v > T) || ((v == T) && (excl < rTie));
        if (v == T) excl++;
        if (pick) {
            u32 slot = atomicAdd(&selCnt, 1u);
            sel[slot] = ((u64)v << 32) | (u32)(NPG - 1 - i);
        }
    }
    __syncthreads();

    if (tid < KOUT) {
        u64 mine = sel[tid];
        int rank = 0;
        for (int j = 0; j < KOUT; j++) rank += (sel[j] > mine);
        u32 v = (u32)(mine >> 32);
        int idx = NPG - 1 - (int)(mine & 0xFFFFFFFFu);
        u32 uu = (v & 0x80000000u) ? (v & 0x7FFFFFFFu) : ~v;
        ordv[rank] = __uint_as_float(uu);
        ordi[rank] = idx;
    }
    __syncthreads();

    for (int t = tid; t < KOUT * 128; t += 1024) {
        int r = t >> 7, c = t & 127;
        int node = g * NPG + ordi[r];
        out[((size_t)g * KOUT + r) * 128 + c] = h[(size_t)node * 128 + c] * ordv[r];
    }
    for (int t = tid; t < KOUT; t += 1024)
        out[(size_t)4 * KOUT * 128 + (size_t)g * KOUT + t] = (float)g;
}

extern "C" void kernel_launch(void* const* d_in, const int* in_sizes, int n_in,
                              void* d_out, int out_size, void* d_ws, size_t ws_size,
                              hipStream_t stream) {
    const float* x        = (const float*)d_in[0];
    const float* mesh_pos = (const float*)d_in[1];
    const int*   edges    = (const int*)d_in[2];
    const float* proj_w   = (const float*)d_in[4];
    const float* proj_b   = (const float*)d_in[5];
    const float* msg_w1   = (const float*)d_in[6];
    const float* msg_b1   = (const float*)d_in[7];
    const float* msg_w2   = (const float*)d_in[8];
    const float* msg_b2   = (const float*)d_in[9];
    const float* upd_w1   = (const float*)d_in[10];
    const float* upd_b1   = (const float*)d_in[11];
    const float* upd_w2   = (const float*)d_in[12];
    const float* upd_b2   = (const float*)d_in[13];
    const float* pool_rel_w  = (const float*)d_in[14];
    const float* pool_rel_b  = (const float*)d_in[15];
    const float* pool_root_w = (const float*)d_in[16];
    float* out = (float*)d_out;

    // workspace: 3 x 16MB node buffers + small arrays (~51.1MB)
    char* w = (char*)d_ws;
    float* h  = (float*)(w);                   // h0 -> h_new (in place)
    float* v  = (float*)(w + (1ull << 24));    // v -> agg
    float* S  = (float*)(w + (2ull << 24));    // u -> S -> q
    char* sm  = w + (3ull << 24);
    int*   deg   = (int*)(sm);
    int*   off   = (int*)(sm + 131072);
    int*   cur   = (int*)(sm + 262144);
    float* rsA   = (float*)(sm + 393216);
    float* bgA   = (float*)(sm + 524288);
    float* pp    = (float*)(sm + 655360);
    float* rr    = (float*)(sm + 786432);
    float* score = (float*)(sm + 917504);
    int*   csr   = (int*)(sm + 1048576);       // 2MB

    k_h0<<<N_NODESC / 2, 256, 0, stream>>>(x, mesh_pos, proj_w, proj_b, h, deg);
    k_deg<<<N_EDGESC / 256, 256, 0, stream>>>(edges, deg);
    k_scan<<<1, 1024, 0, stream>>>(deg, off, cur, rsA, bgA);
    k_fill<<<N_EDGESC / 256, 256, 0, stream>>>(edges, cur, csr);

    // v = h@W1b ; S = h@W1a + b1   (one pass over h, dual out)
    gemm_t<false, true><<<1024, 256, 0, stream>>>(h, msg_w1 + 128 * 128, nullptr, msg_w1,
                                                  msg_b1, nullptr, nullptr, nullptr,
                                                  v, S, 0, nullptr, nullptr, nullptr, nullptr);
    // S[d] = sum_e silu( S[d] + v[src_e] )   (in place)
    k_accum_S<<<N_NODESC / 4, 256, 0, stream>>>(v, csr, off, deg, S);
    // agg = (S@W2)*rs + b2*bg   (into v; v dead after accum)
    gemm_t<false, false><<<1024, 256, 0, stream>>>(S, msg_w2, nullptr, nullptr,
                                                   msg_b2, rsA, bgA, nullptr,
                                                   v, nullptr, 0, nullptr, nullptr, nullptr, nullptr);
    // q = silu( h@U1a + agg@U1b + ub1 )  (into S; S dead after agg gemm)
    gemm_t<true, false><<<1024, 256, 0, stream>>>(h, upd_w1, v, upd_w1 + 128 * 128,
                                                  upd_b1, nullptr, nullptr, nullptr,
                                                  S, nullptr, 1, nullptr, nullptr, nullptr, nullptr);
    // h = h + q@U2 + ub2  (in place) + fused p,r dots
    gemm_t<false, false><<<1024, 256, 0, stream>>>(S, upd_w2, nullptr, nullptr,
                                                   upd_b2, nullptr, nullptr, h,
                                                   h, nullptr, 0, pool_rel_w, pool_root_w, pp, rr);

    k_score<<<N_NODESC / 4, 256, 0, stream>>>(pp, rr, csr, off, deg, pool_rel_b, score);
    k_topk<<<4, 1024, 0, stream>>>(score, h, out);
}

// Round 11
// 434.286 us; speedup vs baseline: 21.2314x; 1.0408x over previous
//
#include <hip/hip_runtime.h>
#include <hip/hip_bf16.h>
#include <math.h>

#define N_NODESC 32768
#define N_EDGESC 524288
#define NPG 8192
#define KOUT 512

typedef unsigned short u16;
typedef unsigned int u32;
typedef unsigned long long u64;

__device__ __forceinline__ float siluf(float x) {
    return x / (1.f + __expf(-x));
}

// ---------------- h0 = x@proj_w + proj_b + sincos(mesh_pos)  (+ zero deg) ----------------
__global__ __launch_bounds__(256) void k_h0(const float* __restrict__ x,
                                            const float* __restrict__ pos,
                                            const float* __restrict__ pw,
                                            const float* __restrict__ pb,
                                            float* __restrict__ h,
                                            int* __restrict__ deg) {
    int gid = blockIdx.x * 256 + threadIdx.x;
    if (gid < N_NODESC) deg[gid] = 0;
    int node = blockIdx.x * 2 + (threadIdx.x >> 7);
    int c = threadIdx.x & 127;
    float x0 = x[node * 3 + 0];
    float x1 = x[node * 3 + 1];
    float x2 = x[node * 3 + 2];
    float acc = x0 * pw[c] + x1 * pw[128 + c] + x2 * pw[256 + c];
    acc += pb[c];
    int dim = c >> 6;
    int inner = c & 63;
    int jj = inner & 31;
    float p = pos[node * 2 + dim];
    float omega = exp2f(-(float)jj * 0.41524101186092027f);
    float ang = p * omega;
    acc += (inner < 32) ? __sinf(ang) : __cosf(ang);
    h[(size_t)node * 128 + c] = acc;
}

// ---------------- degree histogram ----------------
__global__ __launch_bounds__(256) void k_deg(const int* __restrict__ edges, int* __restrict__ deg) {
    int e = blockIdx.x * 256 + threadIdx.x;
    if (e < N_EDGESC) {
        int2 e2 = ((const int2*)edges)[e];
        atomicAdd(&deg[e2.y], 1);
    }
}

// ---------------- exclusive scan (32768 = 1024 threads x 32) ----------------
__global__ __launch_bounds__(1024) void k_scan(const int* __restrict__ deg,
                                               int* __restrict__ off, int* __restrict__ cur,
                                               float* __restrict__ rs, float* __restrict__ bg) {
    __shared__ int ls[1024];
    int tid = threadIdx.x;
    int base = tid * 32;
    int v[32];
    int s = 0;
#pragma unroll
    for (int j = 0; j < 32; j++) { v[j] = deg[base + j]; s += v[j]; }
    ls[tid] = s;
    __syncthreads();
    for (int ofs = 1; ofs < 1024; ofs <<= 1) {
        int t = (tid >= ofs) ? ls[tid - ofs] : 0;
        __syncthreads();
        ls[tid] += t;
        __syncthreads();
    }
    int run = ls[tid] - s;
#pragma unroll
    for (int j = 0; j < 32; j++) {
        off[base + j] = run;
        cur[base + j] = run;
        int d = v[j];
        rs[base + j] = 1.f / (float)(d > 0 ? d : 1);
        bg[base + j] = d > 0 ? 1.f : 0.f;
        run += d;
    }
}

// ---------------- CSR fill (placement order nondeterministic; sorted next) ----------------
__global__ __launch_bounds__(256) void k_fill(const int* __restrict__ edges,
                                              int* __restrict__ cur, int* __restrict__ csr) {
    int e = blockIdx.x * 256 + threadIdx.x;
    if (e < N_EDGESC) {
        int2 e2 = ((const int2*)edges)[e];
        int pos = atomicAdd(&cur[e2.y], 1);
        csr[pos] = e2.x;
    }
}

// ---------------- canonicalize CSR: sort each segment ascending by src ----------------
// Makes all downstream f32 sums bit-deterministic across graph replays
// (atomic fill order varies; sorted order does not; duplicate srcs interchangeable).
__global__ __launch_bounds__(256) void k_sortcsr(int* __restrict__ csr,
                                                 const int* __restrict__ off,
                                                 const int* __restrict__ deg) {
    int d = blockIdx.x * 4 + (threadIdx.x >> 6);
    int lane = threadIdx.x & 63;
    int o = off[d], n = deg[d];
    if (n <= 1) return;
    if (n <= 64) {
        int key = (lane < n) ? csr[o + lane] : 0x7FFFFFFF;
        // wave-wide bitonic sort, 64 lanes
        for (int k = 2; k <= 64; k <<= 1) {
            for (int j = k >> 1; j > 0; j >>= 1) {
                int partner = __shfl_xor(key, j);
                bool asc = ((lane & k) == 0);
                bool keepMin = (((lane & j) == 0) == asc);
                key = keepMin ? min(key, partner) : max(key, partner);
            }
        }
        if (lane < n) csr[o + lane] = key;
    } else {
        // rare fallback (deg > 64): serial insertion sort, still deterministic
        if (lane == 0) {
            for (int i = o + 1; i < o + n; i++) {
                int x = csr[i];
                int j = i - 1;
                while (j >= o && csr[j] > x) { csr[j + 1] = csr[j]; j--; }
                csr[j + 1] = x;
            }
        }
    }
}

// ---------------- W-in-LDS f32 GEMM ----------------
// C = act( (A@W)*rs + bias*bg + resid ), optional fused wrel/wroot row-dots.
// Block: 64 rows x 128 cols; W (64KB) staged in LDS; A ping-pong from global.
__global__ __launch_bounds__(256, 2) void gemm_lds(const float* __restrict__ A, const float* __restrict__ W,
                                                   const float* __restrict__ bias,
                                                   const float* __restrict__ rs, const float* __restrict__ bg,
                                                   const float* __restrict__ resid,
                                                   float* __restrict__ C, int act,
                                                   const float* __restrict__ wrel, const float* __restrict__ wroot,
                                                   float* __restrict__ pout, float* __restrict__ rout) {
    __shared__ float Ws[128 * 128];   // 64KB
    int tid = threadIdx.x;

    {
        const float4* Wg = (const float4*)W;
        float4* Wl = (float4*)Ws;
#pragma unroll
        for (int i = 0; i < 16; i++) Wl[tid + i * 256] = Wg[tid + i * 256];
    }
    __syncthreads();

    int cg = tid & 31;
    int rg = tid >> 5;
    int m0 = blockIdx.x * 64 + rg * 8;
    int c0 = cg * 4;
    const float* Ar = A + (size_t)m0 * 128;

    float acc[8][4];
#pragma unroll
    for (int r = 0; r < 8; r++)
#pragma unroll
        for (int c = 0; c < 4; c++) acc[r][c] = 0.f;

    float4 aA[8], aB[8], wA[4], wB[4];

#define LOAD_A(buf, k)                                                   \
    {                                                                    \
        _Pragma("unroll") for (int r = 0; r < 8; r++)                    \
            buf[r] = *(const float4*)(Ar + r * 128 + (k));               \
    }
#define LOAD_W(buf, k)                                                   \
    {                                                                    \
        _Pragma("unroll") for (int kk = 0; kk < 4; kk++)                 \
            buf[kk] = *(const float4*)(Ws + ((k) + kk) * 128 + c0);      \
    }
#define COMPUTE(ab, wb)                                                  \
    {                                                                    \
        _Pragma("unroll") for (int kk = 0; kk < 4; kk++) {               \
            float4 wv = wb[kk];                                          \
            _Pragma("unroll") for (int r = 0; r < 8; r++) {              \
                float a = ((const float*)&ab[r])[kk];                    \
                acc[r][0] += a * wv.x;                                   \
                acc[r][1] += a * wv.y;                                   \
                acc[r][2] += a * wv.z;                                   \
                acc[r][3] += a * wv.w;                                   \
            }                                                            \
        }                                                                \
    }

    LOAD_A(aA, 0)
    LOAD_W(wA, 0)
    for (int k0 = 0; k0 < 128; k0 += 8) {
        LOAD_A(aB, k0 + 4)
        LOAD_W(wB, k0 + 4)
        COMPUTE(aA, wA)
        if (k0 + 8 < 128) {
            LOAD_A(aA, k0 + 8)
            LOAD_W(wA, k0 + 8)
        }
        COMPUTE(aB, wB)
    }
#undef LOAD_A
#undef LOAD_W
#undef COMPUTE

    float prel[8], prot[8];
#pragma unroll
    for (int r = 0; r < 8; r++) {
        int row = m0 + r;
        float rsv = rs ? rs[row] : 1.f;
        float bgv = bg ? bg[row] : 1.f;
        float4 o;
        float* op = (float*)&o;
#pragma unroll
        for (int c = 0; c < 4; c++) {
            float xv = acc[r][c];
            xv *= rsv;
            if (bias) xv += bias[c0 + c] * bgv;
            if (resid) xv += resid[(size_t)row * 128 + c0 + c];
            if (act) xv = siluf(xv);
            op[c] = xv;
        }
        if (wrel) {
            prel[r] = op[0] * wrel[c0] + op[1] * wrel[c0 + 1] + op[2] * wrel[c0 + 2] + op[3] * wrel[c0 + 3];
            prot[r] = op[0] * wroot[c0] + op[1] * wroot[c0 + 1] + op[2] * wroot[c0 + 2] + op[3] * wroot[c0 + 3];
        }
        *(float4*)(C + (size_t)row * 128 + c0) = o;
    }
    if (wrel) {
#pragma unroll
        for (int r = 0; r < 8; r++) {
            float a = prel[r], b = prot[r];
#pragma unroll
            for (int m = 1; m < 32; m <<= 1) {
                a += __shfl_xor(a, m);
                b += __shfl_xor(b, m);
            }
            if (cg == 0) { pout[m0 + r] = a; rout[m0 + r] = b; }
        }
    }
}

// ---------------- S[d] = sum_{e:dst=d} silu(u[d] + v[src_e]) ; wave per node ----------------
__global__ __launch_bounds__(256) void k_accum_S(const float* __restrict__ v,
                                                 const int* __restrict__ csr, const int* __restrict__ off,
                                                 const int* __restrict__ deg, float* S) {
    int d = blockIdx.x * 4 + (threadIdx.x >> 6);
    int lane = threadIdx.x & 63;
    float* srow = S + (size_t)d * 128;
    float u0 = srow[lane];
    float u1 = srow[64 + lane];
    float a0 = 0.f, a1 = 0.f;
    int o = off[d], n = deg[d];
    for (int base = 0; base < n; base += 64) {
        int cnt = min(64, n - base);
        int sall = (lane < cnt) ? csr[o + base + lane] : 0;
        int s0 = __shfl(sall, 0);
        float p00 = v[(size_t)s0 * 128 + lane];
        float p01 = v[(size_t)s0 * 128 + 64 + lane];
        float p10 = 0.f, p11 = 0.f;
        if (cnt > 1) {
            int s1 = __shfl(sall, 1);
            p10 = v[(size_t)s1 * 128 + lane];
            p11 = v[(size_t)s1 * 128 + 64 + lane];
        }
        for (int j = 0; j < cnt; j++) {
            float cv0 = p00, cv1 = p01;
            p00 = p10; p01 = p11;
            if (j + 2 < cnt) {
                int sn = __shfl(sall, j + 2);
                p10 = v[(size_t)sn * 128 + lane];
                p11 = v[(size_t)sn * 128 + 64 + lane];
            }
            a0 += siluf(u0 + cv0);
            a1 += siluf(u1 + cv1);
        }
    }
    srow[lane] = a0;
    srow[64 + lane] = a1;
}

// ---------------- score[d] = tanh( (sum p[src]) / cnt + rel_b + r[d] ) ----------------
__global__ __launch_bounds__(256) void k_score(const float* __restrict__ p, const float* __restrict__ r,
                                               const int* __restrict__ csr, const int* __restrict__ off,
                                               const int* __restrict__ deg, const float* __restrict__ relb,
                                               float* __restrict__ score) {
    int d = blockIdx.x * 4 + (threadIdx.x >> 6);
    int lane = threadIdx.x & 63;
    int o = off[d], n = deg[d];
    float a = 0.f;
    for (int j = lane; j < n; j += 64) a += p[csr[o + j]];
    for (int m = 32; m > 0; m >>= 1) a += __shfl_xor(a, m);
    if (lane == 0) {
        float cnt = (float)(n > 0 ? n : 1);
        score[d] = tanhf(a / cnt + relb[0] + r[d]);
    }
}

// ---------------- per-graph exact top-k via radix-select + direct ranking ----------------
__global__ __launch_bounds__(1024) void k_topk(const float* __restrict__ score, const float* __restrict__ h,
                                               float* __restrict__ out) {
    __shared__ u32 ms[NPG];
    __shared__ u32 hist[256];
    __shared__ u32 sbuf[1024];
    __shared__ u64 sel[KOUT];
    __shared__ float ordv[KOUT];
    __shared__ int ordi[KOUT];
    __shared__ u32 selCnt, sPrefix, sNeed, sB;

    int g = blockIdx.x;
    int tid = threadIdx.x;

    for (int i = tid; i < NPG; i += 1024) {
        u32 u = __float_as_uint(score[(size_t)g * NPG + i]);
        ms[i] = (u & 0x80000000u) ? ~u : (u | 0x80000000u);
    }
    if (tid == 0) { sNeed = KOUT; sPrefix = 0; selCnt = 0; }
    __syncthreads();

    for (int pass = 0; pass < 4; pass++) {
        int shift = 24 - pass * 8;
        if (tid < 256) hist[tid] = 0;
        __syncthreads();
        u32 pfx = sPrefix;
        for (int i = tid; i < NPG; i += 1024) {
            u32 v = ms[i];
            if (pass == 0 || (v >> (shift + 8)) == pfx)
                atomicAdd(&hist[(v >> shift) & 255u], 1u);
        }
        __syncthreads();
        if (tid < 256) sbuf[tid] = hist[tid];
        __syncthreads();
        for (int ofs = 1; ofs < 256; ofs <<= 1) {
            u32 t = 0;
            if (tid < 256 && tid + ofs < 256) t = sbuf[tid + ofs];
            __syncthreads();
            if (tid < 256) sbuf[tid] += t;
            __syncthreads();
        }
        u32 need = sNeed;
        if (tid < 256) {
            if (sbuf[tid] >= need && (tid == 255 || sbuf[tid + 1] < need)) sB = (u32)tid;
        }
        __syncthreads();
        if (tid == 0) {
            u32 B = sB;
            u32 above = (B == 255) ? 0u : sbuf[B + 1];
            sNeed = need - above;
            sPrefix = (sPrefix << 8) | B;
        }
        __syncthreads();
    }
    u32 T = sPrefix;
    u32 rTie = sNeed;

    int base = tid * 8;
    u32 lc = 0;
#pragma unroll
    for (int j = 0; j < 8; j++) lc += (ms[base + j] == T);
    __syncthreads();
    sbuf[tid] = lc;
    __syncthreads();
    u32 own = lc;
    for (int ofs = 1; ofs < 1024; ofs <<= 1) {
        u32 t = (tid >= ofs) ? sbuf[tid - ofs] : 0;
        __syncthreads();
        sbuf[tid] += t;
        __syncthreads();
    }
    u32 excl = sbuf[tid] - own;

#pragma unroll
    for (int j = 0; j < 8; j++) {
        int i = base + j;
        u32 v = ms[i];
        bool pick = (v > T) || ((v == T) && (excl < rTie));
        if (v == T) excl++;
        if (pick) {
            u32 slot = atomicAdd(&selCnt, 1u);
            sel[slot] = ((u64)v << 32) | (u32)(NPG - 1 - i);
        }
    }
    __syncthreads();

    if (tid < KOUT) {
        u64 mine = sel[tid];
        int rank = 0;
        for (int j = 0; j < KOUT; j++) rank += (sel[j] > mine);
        u32 v = (u32)(mine >> 32);
        int idx = NPG - 1 - (int)(mine & 0xFFFFFFFFu);
        u32 uu = (v & 0x80000000u) ? (v & 0x7FFFFFFFu) : ~v;
        ordv[rank] = __uint_as_float(uu);
        ordi[rank] = idx;
    }
    __syncthreads();

    for (int t = tid; t < KOUT * 128; t += 1024) {
        int r = t >> 7, c = t & 127;
        int node = g * NPG + ordi[r];
        out[((size_t)g * KOUT + r) * 128 + c] = h[(size_t)node * 128 + c] * ordv[r];
    }
    for (int t = tid; t < KOUT; t += 1024)
        out[(size_t)4 * KOUT * 128 + (size_t)g * KOUT + t] = (float)g;
}

extern "C" void kernel_launch(void* const* d_in, const int* in_sizes, int n_in,
                              void* d_out, int out_size, void* d_ws, size_t ws_size,
                              hipStream_t stream) {
    const float* x        = (const float*)d_in[0];
    const float* mesh_pos = (const float*)d_in[1];
    const int*   edges    = (const int*)d_in[2];
    const float* proj_w   = (const float*)d_in[4];
    const float* proj_b   = (const float*)d_in[5];
    const float* msg_w1   = (const float*)d_in[6];
    const float* msg_b1   = (const float*)d_in[7];
    const float* msg_w2   = (const float*)d_in[8];
    const float* msg_b2   = (const float*)d_in[9];
    const float* upd_w1   = (const float*)d_in[10];
    const float* upd_b1   = (const float*)d_in[11];
    const float* upd_w2   = (const float*)d_in[12];
    const float* upd_b2   = (const float*)d_in[13];
    const float* pool_rel_w  = (const float*)d_in[14];
    const float* pool_rel_b  = (const float*)d_in[15];
    const float* pool_root_w = (const float*)d_in[16];
    float* out = (float*)d_out;

    // workspace: 3 x 16MB node buffers + small arrays (~51.1MB)
    char* w = (char*)d_ws;
    float* h  = (float*)(w);                   // h0 -> h_new (in place)
    float* v  = (float*)(w + (1ull << 24));    // v -> agg -> q
    float* S  = (float*)(w + (2ull << 24));    // u -> S -> t
    char* sm  = w + (3ull << 24);
    int*   deg   = (int*)(sm);
    int*   off   = (int*)(sm + 131072);
    int*   cur   = (int*)(sm + 262144);
    float* rsA   = (float*)(sm + 393216);
    float* bgA   = (float*)(sm + 524288);
    float* pp    = (float*)(sm + 655360);
    float* rr    = (float*)(sm + 786432);
    float* score = (float*)(sm + 917504);
    int*   csr   = (int*)(sm + 1048576);       // 2MB

    k_h0<<<N_NODESC / 2, 256, 0, stream>>>(x, mesh_pos, proj_w, proj_b, h, deg);
    k_deg<<<N_EDGESC / 256, 256, 0, stream>>>(edges, deg);
    k_scan<<<1, 1024, 0, stream>>>(deg, off, cur, rsA, bgA);
    k_fill<<<N_EDGESC / 256, 256, 0, stream>>>(edges, cur, csr);
    k_sortcsr<<<N_NODESC / 4, 256, 0, stream>>>(csr, off, deg);

    // v = h@W1b
    gemm_lds<<<512, 256, 0, stream>>>(h, msg_w1 + 128 * 128, nullptr, nullptr, nullptr, nullptr,
                                      v, 0, nullptr, nullptr, nullptr, nullptr);
    // S = h@W1a + b1   (u)
    gemm_lds<<<512, 256, 0, stream>>>(h, msg_w1, msg_b1, nullptr, nullptr, nullptr,
                                      S, 0, nullptr, nullptr, nullptr, nullptr);
    // S[d] = sum_e silu( S[d] + v[src_e] )   (in place)
    k_accum_S<<<N_NODESC / 4, 256, 0, stream>>>(v, csr, off, deg, S);
    // v = (S@W2)*rs + b2*bg   (agg; v dead after accum)
    gemm_lds<<<512, 256, 0, stream>>>(S, msg_w2, msg_b2, rsA, bgA, nullptr,
                                      v, 0, nullptr, nullptr, nullptr, nullptr);
    // S = h@U1a + ub1   (t; S dead after agg gemm)
    gemm_lds<<<512, 256, 0, stream>>>(h, upd_w1, upd_b1, nullptr, nullptr, nullptr,
                                      S, 0, nullptr, nullptr, nullptr, nullptr);
    // v = silu( v@U1b + S )   (q; in place on v)
    gemm_lds<<<512, 256, 0, stream>>>(v, upd_w1 + 128 * 128, nullptr, nullptr, nullptr, S,
                                      v, 1, nullptr, nullptr, nullptr, nullptr);
    // h = h + v@U2 + ub2  (in place) + fused p,r dots
    gemm_lds<<<512, 256, 0, stream>>>(v, upd_w2, upd_b2, nullptr, nullptr, h,
                                      h, 0, pool_rel_w, pool_root_w, pp, rr);

    k_score<<<N_NODESC / 4, 256, 0, stream>>>(pp, rr, csr, off, deg, pool_rel_b, score);
    k_topk<<<4, 1024, 0, stream>>>(score, h, out);
}

// Round 12
// 418.847 us; speedup vs baseline: 22.0140x; 1.0369x over previous
//
#include <hip/hip_runtime.h>
#include <hip/hip_bf16.h>
#include <math.h>

#define N_NODESC 32768
#define N_EDGESC 524288
#define NPG 8192
#define KOUT 512

typedef unsigned short u16;
typedef unsigned int u32;
typedef unsigned long long u64;

__device__ __forceinline__ float siluf(float x) {
    return x / (1.f + __expf(-x));
}

// ---------------- h0 = x@proj_w + proj_b + sincos(mesh_pos)  (+ zero deg) ----------------
__global__ __launch_bounds__(256) void k_h0(const float* __restrict__ x,
                                            const float* __restrict__ pos,
                                            const float* __restrict__ pw,
                                            const float* __restrict__ pb,
                                            float* __restrict__ h,
                                            int* __restrict__ deg) {
    int gid = blockIdx.x * 256 + threadIdx.x;
    if (gid < N_NODESC) deg[gid] = 0;
    int node = blockIdx.x * 2 + (threadIdx.x >> 7);
    int c = threadIdx.x & 127;
    float x0 = x[node * 3 + 0];
    float x1 = x[node * 3 + 1];
    float x2 = x[node * 3 + 2];
    float acc = x0 * pw[c] + x1 * pw[128 + c] + x2 * pw[256 + c];
    acc += pb[c];
    int dim = c >> 6;
    int inner = c & 63;
    int jj = inner & 31;
    float p = pos[node * 2 + dim];
    float omega = exp2f(-(float)jj * 0.41524101186092027f);
    float ang = p * omega;
    acc += (inner < 32) ? __sinf(ang) : __cosf(ang);
    h[(size_t)node * 128 + c] = acc;
}

// ---------------- degree histogram ----------------
__global__ __launch_bounds__(256) void k_deg(const int* __restrict__ edges, int* __restrict__ deg) {
    int e = blockIdx.x * 256 + threadIdx.x;
    if (e < N_EDGESC) {
        int2 e2 = ((const int2*)edges)[e];
        atomicAdd(&deg[e2.y], 1);
    }
}

// ---------------- exclusive scan (32768 = 1024 threads x 32) ----------------
__global__ __launch_bounds__(1024) void k_scan(const int* __restrict__ deg,
                                               int* __restrict__ off, int* __restrict__ cur,
                                               float* __restrict__ rs, float* __restrict__ bg) {
    __shared__ int ls[1024];
    int tid = threadIdx.x;
    int base = tid * 32;
    int v[32];
    int s = 0;
#pragma unroll
    for (int j = 0; j < 32; j++) { v[j] = deg[base + j]; s += v[j]; }
    ls[tid] = s;
    __syncthreads();
    for (int ofs = 1; ofs < 1024; ofs <<= 1) {
        int t = (tid >= ofs) ? ls[tid - ofs] : 0;
        __syncthreads();
        ls[tid] += t;
        __syncthreads();
    }
    int run = ls[tid] - s;
#pragma unroll
    for (int j = 0; j < 32; j++) {
        off[base + j] = run;
        cur[base + j] = run;
        int d = v[j];
        rs[base + j] = 1.f / (float)(d > 0 ? d : 1);
        bg[base + j] = d > 0 ? 1.f : 0.f;
        run += d;
    }
}

// ---------------- CSR fill (placement order nondeterministic; sorted next) ----------------
__global__ __launch_bounds__(256) void k_fill(const int* __restrict__ edges,
                                              int* __restrict__ cur, int* __restrict__ csr) {
    int e = blockIdx.x * 256 + threadIdx.x;
    if (e < N_EDGESC) {
        int2 e2 = ((const int2*)edges)[e];
        int pos = atomicAdd(&cur[e2.y], 1);
        csr[pos] = e2.x;
    }
}

// ---------------- canonicalize CSR: sort each segment ascending by src ----------------
__global__ __launch_bounds__(256) void k_sortcsr(int* __restrict__ csr,
                                                 const int* __restrict__ off,
                                                 const int* __restrict__ deg) {
    int d = blockIdx.x * 4 + (threadIdx.x >> 6);
    int lane = threadIdx.x & 63;
    int o = off[d], n = deg[d];
    if (n <= 1) return;
    if (n <= 64) {
        int key = (lane < n) ? csr[o + lane] : 0x7FFFFFFF;
        for (int k = 2; k <= 64; k <<= 1) {
            for (int j = k >> 1; j > 0; j >>= 1) {
                int partner = __shfl_xor(key, j);
                bool asc = ((lane & k) == 0);
                bool keepMin = (((lane & j) == 0) == asc);
                key = keepMin ? min(key, partner) : max(key, partner);
            }
        }
        if (lane < n) csr[o + lane] = key;
    } else {
        if (lane == 0) {
            for (int i = o + 1; i < o + n; i++) {
                int x = csr[i];
                int j = i - 1;
                while (j >= o && csr[j] > x) { csr[j + 1] = csr[j]; j--; }
                csr[j + 1] = x;
            }
        }
    }
}

// ---------------- W-chunked-LDS f32 GEMM, 32 rows/block for occupancy ----------------
// C = act( (A@W)*rs + bias*bg + resid ), optional fused wrel/wroot row-dots.
// 1024 blocks (4/CU), W staged in 16KB chunks (32 k-rows), same k-ascending
// accumulation order as the 64KB variant -> bitwise-identical results.
__global__ __launch_bounds__(256, 2) void gemm_lds(const float* __restrict__ A, const float* __restrict__ W,
                                                   const float* __restrict__ bias,
                                                   const float* __restrict__ rs, const float* __restrict__ bg,
                                                   const float* __restrict__ resid,
                                                   float* __restrict__ C, int act,
                                                   const float* __restrict__ wrel, const float* __restrict__ wroot,
                                                   float* __restrict__ pout, float* __restrict__ rout) {
    __shared__ float Ws[32 * 128];   // 16KB chunk
    int tid = threadIdx.x;
    int cg = tid & 31;      // 32 col groups x 4 cols
    int rg = tid >> 5;      // 8 row groups x 4 rows
    int m0 = blockIdx.x * 32 + rg * 4;
    int c0 = cg * 4;
    const float* Ar = A + (size_t)m0 * 128;

    float acc[4][4];
#pragma unroll
    for (int r = 0; r < 4; r++)
#pragma unroll
        for (int c = 0; c < 4; c++) acc[r][c] = 0.f;

    float4 aA[4], aB[4], wA[4], wB[4];

#define LOAD_A(buf, k)                                                   \
    {                                                                    \
        _Pragma("unroll") for (int r = 0; r < 4; r++)                    \
            buf[r] = *(const float4*)(Ar + r * 128 + (k));               \
    }
#define LOAD_W(buf, k)                                                   \
    {                                                                    \
        _Pragma("unroll") for (int kk = 0; kk < 4; kk++)                 \
            buf[kk] = *(const float4*)(Ws + ((k) + kk) * 128 + c0);      \
    }
#define COMPUTE(ab, wb)                                                  \
    {                                                                    \
        _Pragma("unroll") for (int kk = 0; kk < 4; kk++) {               \
            float4 wv = wb[kk];                                          \
            _Pragma("unroll") for (int r = 0; r < 4; r++) {              \
                float a = ((const float*)&ab[r])[kk];                    \
                acc[r][0] += a * wv.x;                                   \
                acc[r][1] += a * wv.y;                                   \
                acc[r][2] += a * wv.z;                                   \
                acc[r][3] += a * wv.w;                                   \
            }                                                            \
        }                                                                \
    }

    for (int kc = 0; kc < 128; kc += 32) {
        __syncthreads();   // protect Ws from previous chunk's readers
        {
            const float4* Wg = (const float4*)(W + (size_t)kc * 128);
            float4* Wl = (float4*)Ws;
#pragma unroll
            for (int i = 0; i < 4; i++) Wl[tid + i * 256] = Wg[tid + i * 256];
        }
        __syncthreads();
        LOAD_A(aA, kc)
        LOAD_W(wA, 0)
        for (int k0 = 0; k0 < 32; k0 += 8) {
            LOAD_A(aB, kc + k0 + 4)
            LOAD_W(wB, k0 + 4)
            COMPUTE(aA, wA)
            if (k0 + 8 < 32) {
                LOAD_A(aA, kc + k0 + 8)
                LOAD_W(wA, k0 + 8)
            }
            COMPUTE(aB, wB)
        }
    }
#undef LOAD_A
#undef LOAD_W
#undef COMPUTE

    float prel[4], prot[4];
#pragma unroll
    for (int r = 0; r < 4; r++) {
        int row = m0 + r;
        float rsv = rs ? rs[row] : 1.f;
        float bgv = bg ? bg[row] : 1.f;
        float4 o;
        float* op = (float*)&o;
#pragma unroll
        for (int c = 0; c < 4; c++) {
            float xv = acc[r][c];
            xv *= rsv;
            if (bias) xv += bias[c0 + c] * bgv;
            if (resid) xv += resid[(size_t)row * 128 + c0 + c];
            if (act) xv = siluf(xv);
            op[c] = xv;
        }
        if (wrel) {
            prel[r] = op[0] * wrel[c0] + op[1] * wrel[c0 + 1] + op[2] * wrel[c0 + 2] + op[3] * wrel[c0 + 3];
            prot[r] = op[0] * wroot[c0] + op[1] * wroot[c0 + 1] + op[2] * wroot[c0 + 2] + op[3] * wroot[c0 + 3];
        }
        *(float4*)(C + (size_t)row * 128 + c0) = o;
    }
    if (wrel) {
#pragma unroll
        for (int r = 0; r < 4; r++) {
            float a = prel[r], b = prot[r];
#pragma unroll
            for (int m = 1; m < 32; m <<= 1) {
                a += __shfl_xor(a, m);
                b += __shfl_xor(b, m);
            }
            if (cg == 0) { pout[m0 + r] = a; rout[m0 + r] = b; }
        }
    }
}

// ---------------- S[d] = sum_{e:dst=d} silu(u[d] + v[src_e]) ; wave per node ----------------
// Batch-8 gather: 16 loads in flight, consumed in ascending j (order = r11, bit-identical).
__global__ __launch_bounds__(256) void k_accum_S(const float* __restrict__ v,
                                                 const int* __restrict__ csr, const int* __restrict__ off,
                                                 const int* __restrict__ deg, float* S) {
    int d = blockIdx.x * 4 + (threadIdx.x >> 6);
    int lane = threadIdx.x & 63;
    float* srow = S + (size_t)d * 128;
    float u0 = srow[lane];
    float u1 = srow[64 + lane];
    float a0 = 0.f, a1 = 0.f;
    int o = off[d], n = deg[d];
    for (int base = 0; base < n; base += 64) {
        int cnt = min(64, n - base);
        int sall = (lane < cnt) ? csr[o + base + lane] : 0;
        int j = 0;
        for (; j + 8 <= cnt; j += 8) {
            int s0 = __shfl(sall, j + 0), s1 = __shfl(sall, j + 1);
            int s2 = __shfl(sall, j + 2), s3 = __shfl(sall, j + 3);
            int s4 = __shfl(sall, j + 4), s5 = __shfl(sall, j + 5);
            int s6 = __shfl(sall, j + 6), s7 = __shfl(sall, j + 7);
            float v00 = v[(size_t)s0 * 128 + lane], v01 = v[(size_t)s0 * 128 + 64 + lane];
            float v10 = v[(size_t)s1 * 128 + lane], v11 = v[(size_t)s1 * 128 + 64 + lane];
            float v20 = v[(size_t)s2 * 128 + lane], v21 = v[(size_t)s2 * 128 + 64 + lane];
            float v30 = v[(size_t)s3 * 128 + lane], v31 = v[(size_t)s3 * 128 + 64 + lane];
            float v40 = v[(size_t)s4 * 128 + lane], v41 = v[(size_t)s4 * 128 + 64 + lane];
            float v50 = v[(size_t)s5 * 128 + lane], v51 = v[(size_t)s5 * 128 + 64 + lane];
            float v60 = v[(size_t)s6 * 128 + lane], v61 = v[(size_t)s6 * 128 + 64 + lane];
            float v70 = v[(size_t)s7 * 128 + lane], v71 = v[(size_t)s7 * 128 + 64 + lane];
            a0 += siluf(u0 + v00); a1 += siluf(u1 + v01);
            a0 += siluf(u0 + v10); a1 += siluf(u1 + v11);
            a0 += siluf(u0 + v20); a1 += siluf(u1 + v21);
            a0 += siluf(u0 + v30); a1 += siluf(u1 + v31);
            a0 += siluf(u0 + v40); a1 += siluf(u1 + v41);
            a0 += siluf(u0 + v50); a1 += siluf(u1 + v51);
            a0 += siluf(u0 + v60); a1 += siluf(u1 + v61);
            a0 += siluf(u0 + v70); a1 += siluf(u1 + v71);
        }
        for (; j < cnt; j++) {
            int s = __shfl(sall, j);
            a0 += siluf(u0 + v[(size_t)s * 128 + lane]);
            a1 += siluf(u1 + v[(size_t)s * 128 + 64 + lane]);
        }
    }
    srow[lane] = a0;
    srow[64 + lane] = a1;
}

// ---------------- score[d] = tanh( (sum p[src]) / cnt + rel_b + r[d] ) ----------------
__global__ __launch_bounds__(256) void k_score(const float* __restrict__ p, const float* __restrict__ r,
                                               const int* __restrict__ csr, const int* __restrict__ off,
                                               const int* __restrict__ deg, const float* __restrict__ relb,
                                               float* __restrict__ score) {
    int d = blockIdx.x * 4 + (threadIdx.x >> 6);
    int lane = threadIdx.x & 63;
    int o = off[d], n = deg[d];
    float a = 0.f;
    for (int j = lane; j < n; j += 64) a += p[csr[o + j]];
    for (int m = 32; m > 0; m >>= 1) a += __shfl_xor(a, m);
    if (lane == 0) {
        float cnt = (float)(n > 0 ? n : 1);
        score[d] = tanhf(a / cnt + relb[0] + r[d]);
    }
}

// ---------------- per-graph exact top-k via radix-select + direct ranking ----------------
__global__ __launch_bounds__(1024) void k_topk(const float* __restrict__ score, const float* __restrict__ h,
                                               float* __restrict__ out) {
    __shared__ u32 ms[NPG];
    __shared__ u32 hist[256];
    __shared__ u32 sbuf[1024];
    __shared__ u64 sel[KOUT];
    __shared__ float ordv[KOUT];
    __shared__ int ordi[KOUT];
    __shared__ u32 selCnt, sPrefix, sNeed, sB;

    int g = blockIdx.x;
    int tid = threadIdx.x;

    for (int i = tid; i < NPG; i += 1024) {
        u32 u = __float_as_uint(score[(size_t)g * NPG + i]);
        ms[i] = (u & 0x80000000u) ? ~u : (u | 0x80000000u);
    }
    if (tid == 0) { sNeed = KOUT; sPrefix = 0; selCnt = 0; }
    __syncthreads();

    for (int pass = 0; pass < 4; pass++) {
        int shift = 24 - pass * 8;
        if (tid < 256) hist[tid] = 0;
        __syncthreads();
        u32 pfx = sPrefix;
        for (int i = tid; i < NPG; i += 1024) {
            u32 v = ms[i];
            if (pass == 0 || (v >> (shift + 8)) == pfx)
                atomicAdd(&hist[(v >> shift) & 255u], 1u);
        }
        __syncthreads();
        if (tid < 256) sbuf[tid] = hist[tid];
        __syncthreads();
        for (int ofs = 1; ofs < 256; ofs <<= 1) {
            u32 t = 0;
            if (tid < 256 && tid + ofs < 256) t = sbuf[tid + ofs];
            __syncthreads();
            if (tid < 256) sbuf[tid] += t;
            __syncthreads();
        }
        u32 need = sNeed;
        if (tid < 256) {
            if (sbuf[tid] >= need && (tid == 255 || sbuf[tid + 1] < need)) sB = (u32)tid;
        }
        __syncthreads();
        if (tid == 0) {
            u32 B = sB;
            u32 above = (B == 255) ? 0u : sbuf[B + 1];
            sNeed = need - above;
            sPrefix = (sPrefix << 8) | B;
        }
        __syncthreads();
    }
    u32 T = sPrefix;
    u32 rTie = sNeed;

    int base = tid * 8;
    u32 lc = 0;
#pragma unroll
    for (int j = 0; j < 8; j++) lc += (ms[base + j] == T);
    __syncthreads();
    sbuf[tid] = lc;
    __syncthreads();
    u32 own = lc;
    for (int ofs = 1; ofs < 1024; ofs <<= 1) {
        u32 t = (tid >= ofs) ? sbuf[tid - ofs] : 0;
        __syncthreads();
        sbuf[tid] += t;
        __syncthreads();
    }
    u32 excl = sbuf[tid] - own;

#pragma unroll
    for (int j = 0; j < 8; j++) {
        int i = base + j;
        u32 v = ms[i];
        bool pick = (v > T) || ((v == T) && (excl < rTie));
        if (v == T) excl++;
        if (pick) {
            u32 slot = atomicAdd(&selCnt, 1u);
            sel[slot] = ((u64)v << 32) | (u32)(NPG - 1 - i);
        }
    }
    __syncthreads();

    if (tid < KOUT) {
        u64 mine = sel[tid];
        int rank = 0;
        for (int j = 0; j < KOUT; j++) rank += (sel[j] > mine);
        u32 v = (u32)(mine >> 32);
        int idx = NPG - 1 - (int)(mine & 0xFFFFFFFFu);
        u32 uu = (v & 0x80000000u) ? (v & 0x7FFFFFFFu) : ~v;
        ordv[rank] = __uint_as_float(uu);
        ordi[rank] = idx;
    }
    __syncthreads();

    for (int t = tid; t < KOUT * 128; t += 1024) {
        int r = t >> 7, c = t & 127;
        int node = g * NPG + ordi[r];
        out[((size_t)g * KOUT + r) * 128 + c] = h[(size_t)node * 128 + c] * ordv[r];
    }
    for (int t = tid; t < KOUT; t += 1024)
        out[(size_t)4 * KOUT * 128 + (size_t)g * KOUT + t] = (float)g;
}

extern "C" void kernel_launch(void* const* d_in, const int* in_sizes, int n_in,
                              void* d_out, int out_size, void* d_ws, size_t ws_size,
                              hipStream_t stream) {
    const float* x        = (const float*)d_in[0];
    const float* mesh_pos = (const float*)d_in[1];
    const int*   edges    = (const int*)d_in[2];
    const float* proj_w   = (const float*)d_in[4];
    const float* proj_b   = (const float*)d_in[5];
    const float* msg_w1   = (const float*)d_in[6];
    const float* msg_b1   = (const float*)d_in[7];
    const float* msg_w2   = (const float*)d_in[8];
    const float* msg_b2   = (const float*)d_in[9];
    const float* upd_w1   = (const float*)d_in[10];
    const float* upd_b1   = (const float*)d_in[11];
    const float* upd_w2   = (const float*)d_in[12];
    const float* upd_b2   = (const float*)d_in[13];
    const float* pool_rel_w  = (const float*)d_in[14];
    const float* pool_rel_b  = (const float*)d_in[15];
    const float* pool_root_w = (const float*)d_in[16];
    float* out = (float*)d_out;

    // workspace: 3 x 16MB node buffers + small arrays (~51.1MB)
    char* w = (char*)d_ws;
    float* h  = (float*)(w);                   // h0 -> h_new (in place)
    float* v  = (float*)(w + (1ull << 24));    // v -> agg -> q
    float* S  = (float*)(w + (2ull << 24));    // u -> S -> t
    char* sm  = w + (3ull << 24);
    int*   deg   = (int*)(sm);
    int*   off   = (int*)(sm + 131072);
    int*   cur   = (int*)(sm + 262144);
    float* rsA   = (float*)(sm + 393216);
    float* bgA   = (float*)(sm + 524288);
    float* pp    = (float*)(sm + 655360);
    float* rr    = (float*)(sm + 786432);
    float* score = (float*)(sm + 917504);
    int*   csr   = (int*)(sm + 1048576);       // 2MB

    k_h0<<<N_NODESC / 2, 256, 0, stream>>>(x, mesh_pos, proj_w, proj_b, h, deg);
    k_deg<<<N_EDGESC / 256, 256, 0, stream>>>(edges, deg);
    k_scan<<<1, 1024, 0, stream>>>(deg, off, cur, rsA, bgA);
    k_fill<<<N_EDGESC / 256, 256, 0, stream>>>(edges, cur, csr);
    k_sortcsr<<<N_NODESC / 4, 256, 0, stream>>>(csr, off, deg);

    // v = h@W1b
    gemm_lds<<<1024, 256, 0, stream>>>(h, msg_w1 + 128 * 128, nullptr, nullptr, nullptr, nullptr,
                                       v, 0, nullptr, nullptr, nullptr, nullptr);
    // S = h@W1a + b1   (u)
    gemm_lds<<<1024, 256, 0, stream>>>(h, msg_w1, msg_b1, nullptr, nullptr, nullptr,
                                       S, 0, nullptr, nullptr, nullptr, nullptr);
    // S[d] = sum_e silu( S[d] + v[src_e] )   (in place)
    k_accum_S<<<N_NODESC / 4, 256, 0, stream>>>(v, csr, off, deg, S);
    // v = (S@W2)*rs + b2*bg   (agg; v dead after accum)
    gemm_lds<<<1024, 256, 0, stream>>>(S, msg_w2, msg_b2, rsA, bgA, nullptr,
                                       v, 0, nullptr, nullptr, nullptr, nullptr);
    // S = h@U1a + ub1   (t; S dead after agg gemm)
    gemm_lds<<<1024, 256, 0, stream>>>(h, upd_w1, upd_b1, nullptr, nullptr, nullptr,
                                       S, 0, nullptr, nullptr, nullptr, nullptr);
    // v = silu( v@U1b + S )   (q; in place on v)
    gemm_lds<<<1024, 256, 0, stream>>>(v, upd_w1 + 128 * 128, nullptr, nullptr, nullptr, S,
                                       v, 1, nullptr, nullptr, nullptr, nullptr);
    // h = h + v@U2 + ub2  (in place) + fused p,r dots
    gemm_lds<<<1024, 256, 0, stream>>>(v, upd_w2, upd_b2, nullptr, nullptr, h,
                                       h, 0, pool_rel_w, pool_root_w, pp, rr);

    k_score<<<N_NODESC / 4, 256, 0, stream>>>(pp, rr, csr, off, deg, pool_rel_b, score);
    k_topk<<<4, 1024, 0, stream>>>(score, h, out);
}

// Round 13
// 393.542 us; speedup vs baseline: 23.4295x; 1.0643x over previous
//
#include <hip/hip_runtime.h>
#include <hip/hip_bf16.h>
#include <math.h>

#define N_NODESC 32768
#define N_EDGESC 524288
#define NPG 8192
#define KOUT 512

typedef unsigned short u16;
typedef unsigned int u32;
typedef unsigned long long u64;

__device__ __forceinline__ float siluf(float x) {
    return x / (1.f + __expf(-x));
}

// ---------------- h0 = x@proj_w + proj_b + sincos(mesh_pos)  (+ zero deg) ----------------
__global__ __launch_bounds__(256) void k_h0(const float* __restrict__ x,
                                            const float* __restrict__ pos,
                                            const float* __restrict__ pw,
                                            const float* __restrict__ pb,
                                            float* __restrict__ h,
                                            int* __restrict__ deg) {
    int gid = blockIdx.x * 256 + threadIdx.x;
    if (gid < N_NODESC) deg[gid] = 0;
    int node = blockIdx.x * 2 + (threadIdx.x >> 7);
    int c = threadIdx.x & 127;
    float x0 = x[node * 3 + 0];
    float x1 = x[node * 3 + 1];
    float x2 = x[node * 3 + 2];
    float acc = x0 * pw[c] + x1 * pw[128 + c] + x2 * pw[256 + c];
    acc += pb[c];
    int dim = c >> 6;
    int inner = c & 63;
    int jj = inner & 31;
    float p = pos[node * 2 + dim];
    float omega = exp2f(-(float)jj * 0.41524101186092027f);
    float ang = p * omega;
    acc += (inner < 32) ? __sinf(ang) : __cosf(ang);
    h[(size_t)node * 128 + c] = acc;
}

// ---------------- degree histogram ----------------
__global__ __launch_bounds__(256) void k_deg(const int* __restrict__ edges, int* __restrict__ deg) {
    int e = blockIdx.x * 256 + threadIdx.x;
    if (e < N_EDGESC) {
        int2 e2 = ((const int2*)edges)[e];
        atomicAdd(&deg[e2.y], 1);
    }
}

// ---------------- exclusive scan (32768 = 1024 threads x 32) ----------------
__global__ __launch_bounds__(1024) void k_scan(const int* __restrict__ deg,
                                               int* __restrict__ off, int* __restrict__ cur,
                                               float* __restrict__ rs, float* __restrict__ bg) {
    __shared__ int ls[1024];
    int tid = threadIdx.x;
    int base = tid * 32;
    int v[32];
    int s = 0;
#pragma unroll
    for (int j = 0; j < 32; j++) { v[j] = deg[base + j]; s += v[j]; }
    ls[tid] = s;
    __syncthreads();
    for (int ofs = 1; ofs < 1024; ofs <<= 1) {
        int t = (tid >= ofs) ? ls[tid - ofs] : 0;
        __syncthreads();
        ls[tid] += t;
        __syncthreads();
    }
    int run = ls[tid] - s;
#pragma unroll
    for (int j = 0; j < 32; j++) {
        off[base + j] = run;
        cur[base + j] = run;
        int d = v[j];
        rs[base + j] = 1.f / (float)(d > 0 ? d : 1);
        bg[base + j] = d > 0 ? 1.f : 0.f;
        run += d;
    }
}

// ---------------- CSR fill (placement order nondeterministic; sorted next) ----------------
__global__ __launch_bounds__(256) void k_fill(const int* __restrict__ edges,
                                              int* __restrict__ cur, int* __restrict__ csr) {
    int e = blockIdx.x * 256 + threadIdx.x;
    if (e < N_EDGESC) {
        int2 e2 = ((const int2*)edges)[e];
        int pos = atomicAdd(&cur[e2.y], 1);
        csr[pos] = e2.x;
    }
}

// ---------------- canonicalize CSR: sort each segment ascending by src ----------------
__global__ __launch_bounds__(256) void k_sortcsr(int* __restrict__ csr,
                                                 const int* __restrict__ off,
                                                 const int* __restrict__ deg) {
    int d = blockIdx.x * 4 + (threadIdx.x >> 6);
    int lane = threadIdx.x & 63;
    int o = off[d], n = deg[d];
    if (n <= 1) return;
    if (n <= 64) {
        int key = (lane < n) ? csr[o + lane] : 0x7FFFFFFF;
        for (int k = 2; k <= 64; k <<= 1) {
            for (int j = k >> 1; j > 0; j >>= 1) {
                int partner = __shfl_xor(key, j);
                bool asc = ((lane & k) == 0);
                bool keepMin = (((lane & j) == 0) == asc);
                key = keepMin ? min(key, partner) : max(key, partner);
            }
        }
        if (lane < n) csr[o + lane] = key;
    } else {
        if (lane == 0) {
            for (int i = o + 1; i < o + n; i++) {
                int x = csr[i];
                int j = i - 1;
                while (j >= o && csr[j] > x) { csr[j + 1] = csr[j]; j--; }
                csr[j + 1] = x;
            }
        }
    }
}

// ---------------- dual-W GEMM: V = A@Wv ; U = A@Wu + bu  (one pass over A) ----------------
// 1024 blocks x 256 thr, 32 rows/block, both W tiles chunked 16KB each in LDS.
// Per-output FMA order identical to single-W gemm_lds (k ascending) -> bitwise same.
__global__ __launch_bounds__(256, 2) void gemm_dualw(const float* __restrict__ A,
                                                     const float* __restrict__ Wv,
                                                     const float* __restrict__ Wu,
                                                     const float* __restrict__ bu,
                                                     float* __restrict__ V, float* __restrict__ U) {
    __shared__ float Wsv[32 * 128];
    __shared__ float Wsu[32 * 128];
    int tid = threadIdx.x;
    int cg = tid & 31;
    int rg = tid >> 5;
    int m0 = blockIdx.x * 32 + rg * 4;
    int c0 = cg * 4;
    const float* Ar = A + (size_t)m0 * 128;

    float accv[4][4], accu[4][4];
#pragma unroll
    for (int r = 0; r < 4; r++)
#pragma unroll
        for (int c = 0; c < 4; c++) { accv[r][c] = 0.f; accu[r][c] = 0.f; }

    for (int kc = 0; kc < 128; kc += 32) {
        __syncthreads();
        {
            const float4* Wgv = (const float4*)(Wv + (size_t)kc * 128);
            const float4* Wgu = (const float4*)(Wu + (size_t)kc * 128);
            float4* Wlv = (float4*)Wsv;
            float4* Wlu = (float4*)Wsu;
#pragma unroll
            for (int i = 0; i < 4; i++) {
                Wlv[tid + i * 256] = Wgv[tid + i * 256];
                Wlu[tid + i * 256] = Wgu[tid + i * 256];
            }
        }
        __syncthreads();
#pragma unroll
        for (int k0 = 0; k0 < 32; k0 += 4) {
            float4 a[4];
#pragma unroll
            for (int r = 0; r < 4; r++) a[r] = *(const float4*)(Ar + r * 128 + kc + k0);
#pragma unroll
            for (int kk = 0; kk < 4; kk++) {
                float4 wv = *(const float4*)(Wsv + (k0 + kk) * 128 + c0);
                float4 wu = *(const float4*)(Wsu + (k0 + kk) * 128 + c0);
#pragma unroll
                for (int r = 0; r < 4; r++) {
                    float aa = ((const float*)&a[r])[kk];
                    accv[r][0] += aa * wv.x; accv[r][1] += aa * wv.y;
                    accv[r][2] += aa * wv.z; accv[r][3] += aa * wv.w;
                    accu[r][0] += aa * wu.x; accu[r][1] += aa * wu.y;
                    accu[r][2] += aa * wu.z; accu[r][3] += aa * wu.w;
                }
            }
        }
    }
#pragma unroll
    for (int r = 0; r < 4; r++) {
        int row = m0 + r;
        float4 ov, ou;
        ov.x = accv[r][0]; ov.y = accv[r][1]; ov.z = accv[r][2]; ov.w = accv[r][3];
        ou.x = accu[r][0] + bu[c0];
        ou.y = accu[r][1] + bu[c0 + 1];
        ou.z = accu[r][2] + bu[c0 + 2];
        ou.w = accu[r][3] + bu[c0 + 3];
        *(float4*)(V + (size_t)row * 128 + c0) = ov;
        *(float4*)(U + (size_t)row * 128 + c0) = ou;
    }
}

// ---------------- dual-A GEMM: C = silu( A1@W1 + A2@W2 + bias ) ----------------
// r9-proven association: (acc1 + acc2) + bias, each acc k-ascending.
__global__ __launch_bounds__(256, 2) void gemm_dualA(const float* __restrict__ A1,
                                                     const float* __restrict__ W1,
                                                     const float* __restrict__ A2,
                                                     const float* __restrict__ W2,
                                                     const float* __restrict__ bias,
                                                     float* __restrict__ C) {
    __shared__ float Ws1[32 * 128];
    __shared__ float Ws2[32 * 128];
    int tid = threadIdx.x;
    int cg = tid & 31;
    int rg = tid >> 5;
    int m0 = blockIdx.x * 32 + rg * 4;
    int c0 = cg * 4;
    const float* Ar1 = A1 + (size_t)m0 * 128;
    const float* Ar2 = A2 + (size_t)m0 * 128;

    float acc1[4][4], acc2[4][4];
#pragma unroll
    for (int r = 0; r < 4; r++)
#pragma unroll
        for (int c = 0; c < 4; c++) { acc1[r][c] = 0.f; acc2[r][c] = 0.f; }

    for (int kc = 0; kc < 128; kc += 32) {
        __syncthreads();
        {
            const float4* Wg1 = (const float4*)(W1 + (size_t)kc * 128);
            const float4* Wg2 = (const float4*)(W2 + (size_t)kc * 128);
            float4* Wl1 = (float4*)Ws1;
            float4* Wl2 = (float4*)Ws2;
#pragma unroll
            for (int i = 0; i < 4; i++) {
                Wl1[tid + i * 256] = Wg1[tid + i * 256];
                Wl2[tid + i * 256] = Wg2[tid + i * 256];
            }
        }
        __syncthreads();
#pragma unroll
        for (int k0 = 0; k0 < 32; k0 += 4) {
            float4 a1[4], a2[4];
#pragma unroll
            for (int r = 0; r < 4; r++) {
                a1[r] = *(const float4*)(Ar1 + r * 128 + kc + k0);
                a2[r] = *(const float4*)(Ar2 + r * 128 + kc + k0);
            }
#pragma unroll
            for (int kk = 0; kk < 4; kk++) {
                float4 w1 = *(const float4*)(Ws1 + (k0 + kk) * 128 + c0);
                float4 w2 = *(const float4*)(Ws2 + (k0 + kk) * 128 + c0);
#pragma unroll
                for (int r = 0; r < 4; r++) {
                    float aa = ((const float*)&a1[r])[kk];
                    float bb = ((const float*)&a2[r])[kk];
                    acc1[r][0] += aa * w1.x; acc1[r][1] += aa * w1.y;
                    acc1[r][2] += aa * w1.z; acc1[r][3] += aa * w1.w;
                    acc2[r][0] += bb * w2.x; acc2[r][1] += bb * w2.y;
                    acc2[r][2] += bb * w2.z; acc2[r][3] += bb * w2.w;
                }
            }
        }
    }
#pragma unroll
    for (int r = 0; r < 4; r++) {
        int row = m0 + r;
        float4 o;
        float* op = (float*)&o;
#pragma unroll
        for (int c = 0; c < 4; c++) {
            float xv = acc1[r][c];
            xv += acc2[r][c];
            xv += bias[c0 + c];
            op[c] = siluf(xv);
        }
        *(float4*)(C + (size_t)row * 128 + c0) = o;
    }
}

// ---------------- generic W-chunked-LDS f32 GEMM (r12, unchanged) ----------------
__global__ __launch_bounds__(256, 2) void gemm_lds(const float* __restrict__ A, const float* __restrict__ W,
                                                   const float* __restrict__ bias,
                                                   const float* __restrict__ rs, const float* __restrict__ bg,
                                                   const float* __restrict__ resid,
                                                   float* __restrict__ C, int act,
                                                   const float* __restrict__ wrel, const float* __restrict__ wroot,
                                                   float* __restrict__ pout, float* __restrict__ rout) {
    __shared__ float Ws[32 * 128];
    int tid = threadIdx.x;
    int cg = tid & 31;
    int rg = tid >> 5;
    int m0 = blockIdx.x * 32 + rg * 4;
    int c0 = cg * 4;
    const float* Ar = A + (size_t)m0 * 128;

    float acc[4][4];
#pragma unroll
    for (int r = 0; r < 4; r++)
#pragma unroll
        for (int c = 0; c < 4; c++) acc[r][c] = 0.f;

    float4 aA[4], aB[4], wA[4], wB[4];

#define LOAD_A(buf, k)                                                   \
    {                                                                    \
        _Pragma("unroll") for (int r = 0; r < 4; r++)                    \
            buf[r] = *(const float4*)(Ar + r * 128 + (k));               \
    }
#define LOAD_W(buf, k)                                                   \
    {                                                                    \
        _Pragma("unroll") for (int kk = 0; kk < 4; kk++)                 \
            buf[kk] = *(const float4*)(Ws + ((k) + kk) * 128 + c0);      \
    }
#define COMPUTE(ab, wb)                                                  \
    {                                                                    \
        _Pragma("unroll") for (int kk = 0; kk < 4; kk++) {               \
            float4 wv = wb[kk];                                          \
            _Pragma("unroll") for (int r = 0; r < 4; r++) {              \
                float a = ((const float*)&ab[r])[kk];                    \
                acc[r][0] += a * wv.x;                                   \
                acc[r][1] += a * wv.y;                                   \
                acc[r][2] += a * wv.z;                                   \
                acc[r][3] += a * wv.w;                                   \
            }                                                            \
        }                                                                \
    }

    for (int kc = 0; kc < 128; kc += 32) {
        __syncthreads();
        {
            const float4* Wg = (const float4*)(W + (size_t)kc * 128);
            float4* Wl = (float4*)Ws;
#pragma unroll
            for (int i = 0; i < 4; i++) Wl[tid + i * 256] = Wg[tid + i * 256];
        }
        __syncthreads();
        LOAD_A(aA, kc)
        LOAD_W(wA, 0)
        for (int k0 = 0; k0 < 32; k0 += 8) {
            LOAD_A(aB, kc + k0 + 4)
            LOAD_W(wB, k0 + 4)
            COMPUTE(aA, wA)
            if (k0 + 8 < 32) {
                LOAD_A(aA, kc + k0 + 8)
                LOAD_W(wA, k0 + 8)
            }
            COMPUTE(aB, wB)
        }
    }
#undef LOAD_A
#undef LOAD_W
#undef COMPUTE

    float prel[4], prot[4];
#pragma unroll
    for (int r = 0; r < 4; r++) {
        int row = m0 + r;
        float rsv = rs ? rs[row] : 1.f;
        float bgv = bg ? bg[row] : 1.f;
        float4 o;
        float* op = (float*)&o;
#pragma unroll
        for (int c = 0; c < 4; c++) {
            float xv = acc[r][c];
            xv *= rsv;
            if (bias) xv += bias[c0 + c] * bgv;
            if (resid) xv += resid[(size_t)row * 128 + c0 + c];
            if (act) xv = siluf(xv);
            op[c] = xv;
        }
        if (wrel) {
            prel[r] = op[0] * wrel[c0] + op[1] * wrel[c0 + 1] + op[2] * wrel[c0 + 2] + op[3] * wrel[c0 + 3];
            prot[r] = op[0] * wroot[c0] + op[1] * wroot[c0 + 1] + op[2] * wroot[c0 + 2] + op[3] * wroot[c0 + 3];
        }
        *(float4*)(C + (size_t)row * 128 + c0) = o;
    }
    if (wrel) {
#pragma unroll
        for (int r = 0; r < 4; r++) {
            float a = prel[r], b = prot[r];
#pragma unroll
            for (int m = 1; m < 32; m <<= 1) {
                a += __shfl_xor(a, m);
                b += __shfl_xor(b, m);
            }
            if (cg == 0) { pout[m0 + r] = a; rout[m0 + r] = b; }
        }
    }
}

// ---------------- S[d] = sum_{e:dst=d} silu(u[d] + v[src_e]) ; wave per node ----------------
// float4 half-wave gather: lanes 0-31 = even edges, 32-63 = odd edges; each edge's
// 512B row fetched by one half-wave as 8 float4s. Deterministic combine a_even+a_odd.
__global__ __launch_bounds__(256) void k_accum_S(const float* __restrict__ v,
                                                 const int* __restrict__ csr, const int* __restrict__ off,
                                                 const int* __restrict__ deg, float* S) {
    int d = blockIdx.x * 4 + (threadIdx.x >> 6);
    int lane = threadIdx.x & 63;
    int half = lane >> 5;      // 0: even edges, 1: odd edges
    int l32 = lane & 31;       // dim group: covers dims l32*4 .. l32*4+3
    float* srow = S + (size_t)d * 128;
    float4 u = *(const float4*)(srow + l32 * 4);   // both halves read same addr (broadcast)
    float4 a = {0.f, 0.f, 0.f, 0.f};
    int o = off[d], n = deg[d];
    for (int base = 0; base < n; base += 64) {
        int cnt = min(64, n - base);
        int sall = (lane < cnt) ? csr[o + base + lane] : 0;
        int j = 0;
        for (; j + 8 <= cnt; j += 8) {
            int s0 = __shfl(sall, j + 0 + half);
            int s1 = __shfl(sall, j + 2 + half);
            int s2 = __shfl(sall, j + 4 + half);
            int s3 = __shfl(sall, j + 6 + half);
            float4 v0 = *(const float4*)(v + (size_t)s0 * 128 + l32 * 4);
            float4 v1 = *(const float4*)(v + (size_t)s1 * 128 + l32 * 4);
            float4 v2 = *(const float4*)(v + (size_t)s2 * 128 + l32 * 4);
            float4 v3 = *(const float4*)(v + (size_t)s3 * 128 + l32 * 4);
            a.x += siluf(u.x + v0.x); a.y += siluf(u.y + v0.y);
            a.z += siluf(u.z + v0.z); a.w += siluf(u.w + v0.w);
            a.x += siluf(u.x + v1.x); a.y += siluf(u.y + v1.y);
            a.z += siluf(u.z + v1.z); a.w += siluf(u.w + v1.w);
            a.x += siluf(u.x + v2.x); a.y += siluf(u.y + v2.y);
            a.z += siluf(u.z + v2.z); a.w += siluf(u.w + v2.w);
            a.x += siluf(u.x + v3.x); a.y += siluf(u.y + v3.y);
            a.z += siluf(u.z + v3.z); a.w += siluf(u.w + v3.w);
        }
        for (; j < cnt; j += 2) {
            if (j + 1 < cnt) {   // full pair
                int s = __shfl(sall, j + half);
                float4 vv = *(const float4*)(v + (size_t)s * 128 + l32 * 4);
                a.x += siluf(u.x + vv.x); a.y += siluf(u.y + vv.y);
                a.z += siluf(u.z + vv.z); a.w += siluf(u.w + vv.w);
            } else {             // single tail edge -> lower half only
                int s = __shfl(sall, j);
                if (half == 0) {
                    float4 vv = *(const float4*)(v + (size_t)s * 128 + l32 * 4);
                    a.x += siluf(u.x + vv.x); a.y += siluf(u.y + vv.y);
                    a.z += siluf(u.z + vv.z); a.w += siluf(u.w + vv.w);
                }
            }
        }
    }
    // combine: total = a_even + a_odd (written by lower half: fixed order, deterministic)
    float ox = __shfl(a.x, l32 + 32);
    float oy = __shfl(a.y, l32 + 32);
    float oz = __shfl(a.z, l32 + 32);
    float ow = __shfl(a.w, l32 + 32);
    if (half == 0) {
        float4 t;
        t.x = a.x + ox; t.y = a.y + oy; t.z = a.z + oz; t.w = a.w + ow;
        *(float4*)(srow + l32 * 4) = t;
    }
}

// ---------------- score[d] = tanh( (sum p[src]) / cnt + rel_b + r[d] ) ----------------
__global__ __launch_bounds__(256) void k_score(const float* __restrict__ p, const float* __restrict__ r,
                                               const int* __restrict__ csr, const int* __restrict__ off,
                                               const int* __restrict__ deg, const float* __restrict__ relb,
                                               float* __restrict__ score) {
    int d = blockIdx.x * 4 + (threadIdx.x >> 6);
    int lane = threadIdx.x & 63;
    int o = off[d], n = deg[d];
    float a = 0.f;
    for (int j = lane; j < n; j += 64) a += p[csr[o + j]];
    for (int m = 32; m > 0; m >>= 1) a += __shfl_xor(a, m);
    if (lane == 0) {
        float cnt = (float)(n > 0 ? n : 1);
        score[d] = tanhf(a / cnt + relb[0] + r[d]);
    }
}

// ---------------- per-graph exact top-k via radix-select + direct ranking ----------------
__global__ __launch_bounds__(1024) void k_topk(const float* __restrict__ score, const float* __restrict__ h,
                                               float* __restrict__ out) {
    __shared__ u32 ms[NPG];
    __shared__ u32 hist[256];
    __shared__ u32 sbuf[1024];
    __shared__ u64 sel[KOUT];
    __shared__ float ordv[KOUT];
    __shared__ int ordi[KOUT];
    __shared__ u32 selCnt, sPrefix, sNeed, sB;

    int g = blockIdx.x;
    int tid = threadIdx.x;

    for (int i = tid; i < NPG; i += 1024) {
        u32 u = __float_as_uint(score[(size_t)g * NPG + i]);
        ms[i] = (u & 0x80000000u) ? ~u : (u | 0x80000000u);
    }
    if (tid == 0) { sNeed = KOUT; sPrefix = 0; selCnt = 0; }
    __syncthreads();

    for (int pass = 0; pass < 4; pass++) {
        int shift = 24 - pass * 8;
        if (tid < 256) hist[tid] = 0;
        __syncthreads();
        u32 pfx = sPrefix;
        for (int i = tid; i < NPG; i += 1024) {
            u32 v = ms[i];
            if (pass == 0 || (v >> (shift + 8)) == pfx)
                atomicAdd(&hist[(v >> shift) & 255u], 1u);
        }
        __syncthreads();
        if (tid < 256) sbuf[tid] = hist[tid];
        __syncthreads();
        for (int ofs = 1; ofs < 256; ofs <<= 1) {
            u32 t = 0;
            if (tid < 256 && tid + ofs < 256) t = sbuf[tid + ofs];
            __syncthreads();
            if (tid < 256) sbuf[tid] += t;
            __syncthreads();
        }
        u32 need = sNeed;
        if (tid < 256) {
            if (sbuf[tid] >= need && (tid == 255 || sbuf[tid + 1] < need)) sB = (u32)tid;
        }
        __syncthreads();
        if (tid == 0) {
            u32 B = sB;
            u32 above = (B == 255) ? 0u : sbuf[B + 1];
            sNeed = need - above;
            sPrefix = (sPrefix << 8) | B;
        }
        __syncthreads();
    }
    u32 T = sPrefix;
    u32 rTie = sNeed;

    int base = tid * 8;
    u32 lc = 0;
#pragma unroll
    for (int j = 0; j < 8; j++) lc += (ms[base + j] == T);
    __syncthreads();
    sbuf[tid] = lc;
    __syncthreads();
    u32 own = lc;
    for (int ofs = 1; ofs < 1024; ofs <<= 1) {
        u32 t = (tid >= ofs) ? sbuf[tid - ofs] : 0;
        __syncthreads();
        sbuf[tid] += t;
        __syncthreads();
    }
    u32 excl = sbuf[tid] - own;

#pragma unroll
    for (int j = 0; j < 8; j++) {
        int i = base + j;
        u32 v = ms[i];
        bool pick = (v > T) || ((v == T) && (excl < rTie));
        if (v == T) excl++;
        if (pick) {
            u32 slot = atomicAdd(&selCnt, 1u);
            sel[slot] = ((u64)v << 32) | (u32)(NPG - 1 - i);
        }
    }
    __syncthreads();

    if (tid < KOUT) {
        u64 mine = sel[tid];
        int rank = 0;
        for (int j = 0; j < KOUT; j++) rank += (sel[j] > mine);
        u32 v = (u32)(mine >> 32);
        int idx = NPG - 1 - (int)(mine & 0xFFFFFFFFu);
        u32 uu = (v & 0x80000000u) ? (v & 0x7FFFFFFFu) : ~v;
        ordv[rank] = __uint_as_float(uu);
        ordi[rank] = idx;
    }
    __syncthreads();

    for (int t = tid; t < KOUT * 128; t += 1024) {
        int r = t >> 7, c = t & 127;
        int node = g * NPG + ordi[r];
        out[((size_t)g * KOUT + r) * 128 + c] = h[(size_t)node * 128 + c] * ordv[r];
    }
    for (int t = tid; t < KOUT; t += 1024)
        out[(size_t)4 * KOUT * 128 + (size_t)g * KOUT + t] = (float)g;
}

extern "C" void kernel_launch(void* const* d_in, const int* in_sizes, int n_in,
                              void* d_out, int out_size, void* d_ws, size_t ws_size,
                              hipStream_t stream) {
    const float* x        = (const float*)d_in[0];
    const float* mesh_pos = (const float*)d_in[1];
    const int*   edges    = (const int*)d_in[2];
    const float* proj_w   = (const float*)d_in[4];
    const float* proj_b   = (const float*)d_in[5];
    const float* msg_w1   = (const float*)d_in[6];
    const float* msg_b1   = (const float*)d_in[7];
    const float* msg_w2   = (const float*)d_in[8];
    const float* msg_b2   = (const float*)d_in[9];
    const float* upd_w1   = (const float*)d_in[10];
    const float* upd_b1   = (const float*)d_in[11];
    const float* upd_w2   = (const float*)d_in[12];
    const float* upd_b2   = (const float*)d_in[13];
    const float* pool_rel_w  = (const float*)d_in[14];
    const float* pool_rel_b  = (const float*)d_in[15];
    const float* pool_root_w = (const float*)d_in[16];
    float* out = (float*)d_out;

    // workspace: 3 x 16MB node buffers + small arrays (~51.1MB)
    char* w = (char*)d_ws;
    float* h  = (float*)(w);                   // h0 -> h_new (in place)
    float* v  = (float*)(w + (1ull << 24));    // v -> agg
    float* S  = (float*)(w + (2ull << 24));    // u -> S -> q
    char* sm  = w + (3ull << 24);
    int*   deg   = (int*)(sm);
    int*   off   = (int*)(sm + 131072);
    int*   cur   = (int*)(sm + 262144);
    float* rsA   = (float*)(sm + 393216);
    float* bgA   = (float*)(sm + 524288);
    float* pp    = (float*)(sm + 655360);
    float* rr    = (float*)(sm + 786432);
    float* score = (float*)(sm + 917504);
    int*   csr   = (int*)(sm + 1048576);       // 2MB

    k_h0<<<N_NODESC / 2, 256, 0, stream>>>(x, mesh_pos, proj_w, proj_b, h, deg);
    k_deg<<<N_EDGESC / 256, 256, 0, stream>>>(edges, deg);
    k_scan<<<1, 1024, 0, stream>>>(deg, off, cur, rsA, bgA);
    k_fill<<<N_EDGESC / 256, 256, 0, stream>>>(edges, cur, csr);
    k_sortcsr<<<N_NODESC / 4, 256, 0, stream>>>(csr, off, deg);

    // v = h@W1b ; S = h@W1a + b1   (one pass over h)
    gemm_dualw<<<1024, 256, 0, stream>>>(h, msg_w1 + 128 * 128, msg_w1, msg_b1, v, S);
    // S[d] = sum_e silu( S[d] + v[src_e] )   (in place)
    k_accum_S<<<N_NODESC / 4, 256, 0, stream>>>(v, csr, off, deg, S);
    // v = (S@W2)*rs + b2*bg   (agg; v dead after accum)
    gemm_lds<<<1024, 256, 0, stream>>>(S, msg_w2, msg_b2, rsA, bgA, nullptr,
                                       v, 0, nullptr, nullptr, nullptr, nullptr);
    // S = silu( h@U1a + agg@U1b + ub1 )   (q; S dead after agg gemm; r9 association)
    gemm_dualA<<<1024, 256, 0, stream>>>(h, upd_w1, v, upd_w1 + 128 * 128, upd_b1, S);
    // h = h + q@U2 + ub2  (in place) + fused p,r dots
    gemm_lds<<<1024, 256, 0, stream>>>(S, upd_w2, upd_b2, nullptr, nullptr, h,
                                       h, 0, pool_rel_w, pool_root_w, pp, rr);

    k_score<<<N_NODESC / 4, 256, 0, stream>>>(pp, rr, csr, off, deg, pool_rel_b, score);
    k_topk<<<4, 1024, 0, stream>>>(score, h, out);
}

// Round 14
// 386.571 us; speedup vs baseline: 23.8521x; 1.0180x over previous
//
#include <hip/hip_runtime.h>
#include <hip/hip_bf16.h>
#include <math.h>

#define N_NODESC 32768
#define N_EDGESC 524288
#define NPG 8192
#define KOUT 512

typedef unsigned short u16;
typedef unsigned int u32;
typedef unsigned long long u64;

__device__ __forceinline__ float siluf(float x) {
    return x / (1.f + __expf(-x));
}

// ---------------- h0 = x@proj_w + proj_b + sincos(mesh_pos)  (+ zero deg) ----------------
__global__ __launch_bounds__(256) void k_h0(const float* __restrict__ x,
                                            const float* __restrict__ pos,
                                            const float* __restrict__ pw,
                                            const float* __restrict__ pb,
                                            float* __restrict__ h,
                                            int* __restrict__ deg) {
    int gid = blockIdx.x * 256 + threadIdx.x;
    if (gid < N_NODESC) deg[gid] = 0;
    int node = blockIdx.x * 2 + (threadIdx.x >> 7);
    int c = threadIdx.x & 127;
    float x0 = x[node * 3 + 0];
    float x1 = x[node * 3 + 1];
    float x2 = x[node * 3 + 2];
    float acc = x0 * pw[c] + x1 * pw[128 + c] + x2 * pw[256 + c];
    acc += pb[c];
    int dim = c >> 6;
    int inner = c & 63;
    int jj = inner & 31;
    float p = pos[node * 2 + dim];
    float omega = exp2f(-(float)jj * 0.41524101186092027f);
    float ang = p * omega;
    acc += (inner < 32) ? __sinf(ang) : __cosf(ang);
    h[(size_t)node * 128 + c] = acc;
}

// ---------------- degree histogram ----------------
__global__ __launch_bounds__(256) void k_deg(const int* __restrict__ edges, int* __restrict__ deg) {
    int e = blockIdx.x * 256 + threadIdx.x;
    if (e < N_EDGESC) {
        int2 e2 = ((const int2*)edges)[e];
        atomicAdd(&deg[e2.y], 1);
    }
}

// ---------------- exclusive scan (32768 = 1024 threads x 32) ----------------
__global__ __launch_bounds__(1024) void k_scan(const int* __restrict__ deg,
                                               int* __restrict__ off, int* __restrict__ cur,
                                               float* __restrict__ rs, float* __restrict__ bg) {
    __shared__ int ls[1024];
    int tid = threadIdx.x;
    int base = tid * 32;
    int v[32];
    int s = 0;
#pragma unroll
    for (int j = 0; j < 32; j++) { v[j] = deg[base + j]; s += v[j]; }
    ls[tid] = s;
    __syncthreads();
    for (int ofs = 1; ofs < 1024; ofs <<= 1) {
        int t = (tid >= ofs) ? ls[tid - ofs] : 0;
        __syncthreads();
        ls[tid] += t;
        __syncthreads();
    }
    int run = ls[tid] - s;
#pragma unroll
    for (int j = 0; j < 32; j++) {
        off[base + j] = run;
        cur[base + j] = run;
        int d = v[j];
        rs[base + j] = 1.f / (float)(d > 0 ? d : 1);
        bg[base + j] = d > 0 ? 1.f : 0.f;
        run += d;
    }
}

// ---------------- CSR fill (placement order nondeterministic; sorted next) ----------------
__global__ __launch_bounds__(256) void k_fill(const int* __restrict__ edges,
                                              int* __restrict__ cur, int* __restrict__ csr) {
    int e = blockIdx.x * 256 + threadIdx.x;
    if (e < N_EDGESC) {
        int2 e2 = ((const int2*)edges)[e];
        int pos = atomicAdd(&cur[e2.y], 1);
        csr[pos] = e2.x;
    }
}

// ---------------- canonicalize CSR: sort each segment ascending by src ----------------
__global__ __launch_bounds__(256) void k_sortcsr(int* __restrict__ csr,
                                                 const int* __restrict__ off,
                                                 const int* __restrict__ deg) {
    int d = blockIdx.x * 4 + (threadIdx.x >> 6);
    int lane = threadIdx.x & 63;
    int o = off[d], n = deg[d];
    if (n <= 1) return;
    if (n <= 64) {
        int key = (lane < n) ? csr[o + lane] : 0x7FFFFFFF;
        for (int k = 2; k <= 64; k <<= 1) {
            for (int j = k >> 1; j > 0; j >>= 1) {
                int partner = __shfl_xor(key, j);
                bool asc = ((lane & k) == 0);
                bool keepMin = (((lane & j) == 0) == asc);
                key = keepMin ? min(key, partner) : max(key, partner);
            }
        }
        if (lane < n) csr[o + lane] = key;
    } else {
        if (lane == 0) {
            for (int i = o + 1; i < o + n; i++) {
                int x = csr[i];
                int j = i - 1;
                while (j >= o && csr[j] > x) { csr[j + 1] = csr[j]; j--; }
                csr[j + 1] = x;
            }
        }
    }
}

// ---------------- dual-W GEMM: V = A@Wv ; U = A@Wu + bu  (one pass over A) ----------------
__global__ __launch_bounds__(256, 2) void gemm_dualw(const float* __restrict__ A,
                                                     const float* __restrict__ Wv,
                                                     const float* __restrict__ Wu,
                                                     const float* __restrict__ bu,
                                                     float* __restrict__ V, float* __restrict__ U) {
    __shared__ float Wsv[32 * 128];
    __shared__ float Wsu[32 * 128];
    int tid = threadIdx.x;
    int cg = tid & 31;
    int rg = tid >> 5;
    int m0 = blockIdx.x * 32 + rg * 4;
    int c0 = cg * 4;
    const float* Ar = A + (size_t)m0 * 128;

    float accv[4][4], accu[4][4];
#pragma unroll
    for (int r = 0; r < 4; r++)
#pragma unroll
        for (int c = 0; c < 4; c++) { accv[r][c] = 0.f; accu[r][c] = 0.f; }

    for (int kc = 0; kc < 128; kc += 32) {
        __syncthreads();
        {
            const float4* Wgv = (const float4*)(Wv + (size_t)kc * 128);
            const float4* Wgu = (const float4*)(Wu + (size_t)kc * 128);
            float4* Wlv = (float4*)Wsv;
            float4* Wlu = (float4*)Wsu;
#pragma unroll
            for (int i = 0; i < 4; i++) {
                Wlv[tid + i * 256] = Wgv[tid + i * 256];
                Wlu[tid + i * 256] = Wgu[tid + i * 256];
            }
        }
        __syncthreads();
#pragma unroll
        for (int k0 = 0; k0 < 32; k0 += 4) {
            float4 a[4];
#pragma unroll
            for (int r = 0; r < 4; r++) a[r] = *(const float4*)(Ar + r * 128 + kc + k0);
#pragma unroll
            for (int kk = 0; kk < 4; kk++) {
                float4 wv = *(const float4*)(Wsv + (k0 + kk) * 128 + c0);
                float4 wu = *(const float4*)(Wsu + (k0 + kk) * 128 + c0);
#pragma unroll
                for (int r = 0; r < 4; r++) {
                    float aa = ((const float*)&a[r])[kk];
                    accv[r][0] += aa * wv.x; accv[r][1] += aa * wv.y;
                    accv[r][2] += aa * wv.z; accv[r][3] += aa * wv.w;
                    accu[r][0] += aa * wu.x; accu[r][1] += aa * wu.y;
                    accu[r][2] += aa * wu.z; accu[r][3] += aa * wu.w;
                }
            }
        }
    }
#pragma unroll
    for (int r = 0; r < 4; r++) {
        int row = m0 + r;
        float4 ov, ou;
        ov.x = accv[r][0]; ov.y = accv[r][1]; ov.z = accv[r][2]; ov.w = accv[r][3];
        ou.x = accu[r][0] + bu[c0];
        ou.y = accu[r][1] + bu[c0 + 1];
        ou.z = accu[r][2] + bu[c0 + 2];
        ou.w = accu[r][3] + bu[c0 + 3];
        *(float4*)(V + (size_t)row * 128 + c0) = ov;
        *(float4*)(U + (size_t)row * 128 + c0) = ou;
    }
}

// ---------------- fused post-accum chain: agg -> q -> h_new, one kernel ----------------
// stage1: aggT = (S@W2)*rs + b2*bg          (LDS tile)
// stage2: q = silu( h@U1a + aggT@U1b + ub1 ) (LDS tile, overwrites aggT)
// stage3: h = h + qT@U2 + ub2  + fused p/r dots
// Every accumulator's FMA sequence is k-ascending; epilogue order copied from r13
// gemm_lds/dualA -> output bit-identical to the 3-launch version.
__global__ __launch_bounds__(256, 2) void gemm_chain(const float* __restrict__ S,
                                                     float* __restrict__ h,
                                                     const float* __restrict__ W2,
                                                     const float* __restrict__ b2,
                                                     const float* __restrict__ rs,
                                                     const float* __restrict__ bg,
                                                     const float* __restrict__ U1a,
                                                     const float* __restrict__ U1b,
                                                     const float* __restrict__ ub1,
                                                     const float* __restrict__ U2,
                                                     const float* __restrict__ ub2,
                                                     const float* __restrict__ wrel,
                                                     const float* __restrict__ wroot,
                                                     float* __restrict__ pout,
                                                     float* __restrict__ rout) {
    __shared__ float Wc[32 * 128];   // 16KB rotating weight chunk
    __shared__ float T[32 * 128];    // 16KB tile: agg, then q
    int tid = threadIdx.x;
    int cg = tid & 31;
    int rg = tid >> 5;
    int m0 = blockIdx.x * 32 + rg * 4;
    int c0 = cg * 4;
    const float* Sr = S + (size_t)m0 * 128;
    const float* hr = h + (size_t)m0 * 128;

    float acc1[4][4], acc2[4][4];

#define ZERO(acc)                                                        \
    {                                                                    \
        _Pragma("unroll") for (int r = 0; r < 4; r++)                    \
            _Pragma("unroll") for (int c = 0; c < 4; c++) acc[r][c] = 0.f; \
    }
#define STAGE_W(Wsrc, kc)                                                \
    {                                                                    \
        __syncthreads();                                                 \
        const float4* Wg = (const float4*)((Wsrc) + (size_t)(kc) * 128); \
        float4* Wl = (float4*)Wc;                                        \
        _Pragma("unroll") for (int i = 0; i < 4; i++)                    \
            Wl[tid + i * 256] = Wg[tid + i * 256];                       \
        __syncthreads();                                                 \
    }
#define COMPUTE_G(acc, Abase, kc)                                        \
    {                                                                    \
        _Pragma("unroll") for (int k0 = 0; k0 < 32; k0 += 4) {           \
            float4 a[4];                                                 \
            _Pragma("unroll") for (int r = 0; r < 4; r++)                \
                a[r] = *(const float4*)((Abase) + r * 128 + (kc) + k0);  \
            _Pragma("unroll") for (int kk = 0; kk < 4; kk++) {           \
                float4 wv = *(const float4*)(Wc + (k0 + kk) * 128 + c0); \
                _Pragma("unroll") for (int r = 0; r < 4; r++) {          \
                    float aa = ((const float*)&a[r])[kk];                \
                    acc[r][0] += aa * wv.x; acc[r][1] += aa * wv.y;      \
                    acc[r][2] += aa * wv.z; acc[r][3] += aa * wv.w;      \
                }                                                        \
            }                                                            \
        }                                                                \
    }
#define COMPUTE_T(acc, kc)                                               \
    {                                                                    \
        _Pragma("unroll") for (int k0 = 0; k0 < 32; k0 += 4) {           \
            float4 a[4];                                                 \
            _Pragma("unroll") for (int r = 0; r < 4; r++)                \
                a[r] = *(const float4*)(T + (rg * 4 + r) * 128 + (kc) + k0); \
            _Pragma("unroll") for (int kk = 0; kk < 4; kk++) {           \
                float4 wv = *(const float4*)(Wc + (k0 + kk) * 128 + c0); \
                _Pragma("unroll") for (int r = 0; r < 4; r++) {          \
                    float aa = ((const float*)&a[r])[kk];                \
                    acc[r][0] += aa * wv.x; acc[r][1] += aa * wv.y;      \
                    acc[r][2] += aa * wv.z; acc[r][3] += aa * wv.w;      \
                }                                                        \
            }                                                            \
        }                                                                \
    }

    // ---- stage 1: acc1 = S@W2 ; aggT = acc1*rs + b2*bg ----
    ZERO(acc1)
    for (int kc = 0; kc < 128; kc += 32) {
        STAGE_W(W2, kc)
        COMPUTE_G(acc1, Sr, kc)
    }
#pragma unroll
    for (int r = 0; r < 4; r++) {
        int row = m0 + r;
        float rsv = rs[row];
        float bgv = bg[row];
        float4 o;
        float* op = (float*)&o;
#pragma unroll
        for (int c = 0; c < 4; c++) {
            float xv = acc1[r][c];
            xv *= rsv;                       // r13 gemm_lds epilogue order
            xv += b2[c0 + c] * bgv;
            op[c] = xv;
        }
        *(float4*)(T + (rg * 4 + r) * 128 + c0) = o;
    }
    __syncthreads();   // aggT visible to all waves

    // ---- stage 2: acc1 = h@U1a ; acc2 = aggT@U1b ; q = silu(acc1+acc2+ub1) ----
    ZERO(acc1)
    for (int kc = 0; kc < 128; kc += 32) {
        STAGE_W(U1a, kc)
        COMPUTE_G(acc1, hr, kc)
    }
    ZERO(acc2)
    for (int kc = 0; kc < 128; kc += 32) {
        STAGE_W(U1b, kc)
        COMPUTE_T(acc2, kc)
    }
    __syncthreads();   // all waves done reading aggT before overwrite
#pragma unroll
    for (int r = 0; r < 4; r++) {
        float4 o;
        float* op = (float*)&o;
#pragma unroll
        for (int c = 0; c < 4; c++) {
            float xv = acc1[r][c];           // r13 dualA epilogue order
            xv += acc2[r][c];
            xv += ub1[c0 + c];
            op[c] = siluf(xv);
        }
        *(float4*)(T + (rg * 4 + r) * 128 + c0) = o;
    }
    __syncthreads();   // qT visible

    // ---- stage 3: acc1 = qT@U2 ; h = acc1 + ub2 + h ; p/r dots ----
    ZERO(acc1)
    for (int kc = 0; kc < 128; kc += 32) {
        STAGE_W(U2, kc)
        COMPUTE_T(acc1, kc)
    }
    float prel[4], prot[4];
#pragma unroll
    for (int r = 0; r < 4; r++) {
        int row = m0 + r;
        float4 o;
        float* op = (float*)&o;
#pragma unroll
        for (int c = 0; c < 4; c++) {
            float xv = acc1[r][c];
            xv *= 1.f;                       // matches r13 gemm_lds (rs=null path)
            xv += ub2[c0 + c] * 1.f;
            xv += hr[r * 128 + c0 + c];
            op[c] = xv;
        }
        prel[r] = op[0] * wrel[c0] + op[1] * wrel[c0 + 1] + op[2] * wrel[c0 + 2] + op[3] * wrel[c0 + 3];
        prot[r] = op[0] * wroot[c0] + op[1] * wroot[c0 + 1] + op[2] * wroot[c0 + 2] + op[3] * wroot[c0 + 3];
        *(float4*)(h + (size_t)row * 128 + c0) = o;
    }
#pragma unroll
    for (int r = 0; r < 4; r++) {
        float a = prel[r], b = prot[r];
#pragma unroll
        for (int m = 1; m < 32; m <<= 1) {
            a += __shfl_xor(a, m);
            b += __shfl_xor(b, m);
        }
        if (cg == 0) { pout[m0 + r] = a; rout[m0 + r] = b; }
    }
#undef ZERO
#undef STAGE_W
#undef COMPUTE_G
#undef COMPUTE_T
}

// ---------------- S[d] = sum_{e:dst=d} silu(u[d] + v[src_e]) ; wave per node ----------------
// (r13 version kept byte-identical: preserves S bit pattern)
__global__ __launch_bounds__(256) void k_accum_S(const float* __restrict__ v,
                                                 const int* __restrict__ csr, const int* __restrict__ off,
                                                 const int* __restrict__ deg, float* S) {
    int d = blockIdx.x * 4 + (threadIdx.x >> 6);
    int lane = threadIdx.x & 63;
    int half = lane >> 5;
    int l32 = lane & 31;
    float* srow = S + (size_t)d * 128;
    float4 u = *(const float4*)(srow + l32 * 4);
    float4 a = {0.f, 0.f, 0.f, 0.f};
    int o = off[d], n = deg[d];
    for (int base = 0; base < n; base += 64) {
        int cnt = min(64, n - base);
        int sall = (lane < cnt) ? csr[o + base + lane] : 0;
        int j = 0;
        for (; j + 8 <= cnt; j += 8) {
            int s0 = __shfl(sall, j + 0 + half);
            int s1 = __shfl(sall, j + 2 + half);
            int s2 = __shfl(sall, j + 4 + half);
            int s3 = __shfl(sall, j + 6 + half);
            float4 v0 = *(const float4*)(v + (size_t)s0 * 128 + l32 * 4);
            float4 v1 = *(const float4*)(v + (size_t)s1 * 128 + l32 * 4);
            float4 v2 = *(const float4*)(v + (size_t)s2 * 128 + l32 * 4);
            float4 v3 = *(const float4*)(v + (size_t)s3 * 128 + l32 * 4);
            a.x += siluf(u.x + v0.x); a.y += siluf(u.y + v0.y);
            a.z += siluf(u.z + v0.z); a.w += siluf(u.w + v0.w);
            a.x += siluf(u.x + v1.x); a.y += siluf(u.y + v1.y);
            a.z += siluf(u.z + v1.z); a.w += siluf(u.w + v1.w);
            a.x += siluf(u.x + v2.x); a.y += siluf(u.y + v2.y);
            a.z += siluf(u.z + v2.z); a.w += siluf(u.w + v2.w);
            a.x += siluf(u.x + v3.x); a.y += siluf(u.y + v3.y);
            a.z += siluf(u.z + v3.z); a.w += siluf(u.w + v3.w);
        }
        for (; j < cnt; j += 2) {
            if (j + 1 < cnt) {
                int s = __shfl(sall, j + half);
                float4 vv = *(const float4*)(v + (size_t)s * 128 + l32 * 4);
                a.x += siluf(u.x + vv.x); a.y += siluf(u.y + vv.y);
                a.z += siluf(u.z + vv.z); a.w += siluf(u.w + vv.w);
            } else {
                int s = __shfl(sall, j);
                if (half == 0) {
                    float4 vv = *(const float4*)(v + (size_t)s * 128 + l32 * 4);
                    a.x += siluf(u.x + vv.x); a.y += siluf(u.y + vv.y);
                    a.z += siluf(u.z + vv.z); a.w += siluf(u.w + vv.w);
                }
            }
        }
    }
    float ox = __shfl(a.x, l32 + 32);
    float oy = __shfl(a.y, l32 + 32);
    float oz = __shfl(a.z, l32 + 32);
    float ow = __shfl(a.w, l32 + 32);
    if (half == 0) {
        float4 t;
        t.x = a.x + ox; t.y = a.y + oy; t.z = a.z + oz; t.w = a.w + ow;
        *(float4*)(srow + l32 * 4) = t;
    }
}

// ---------------- score[d] = tanh( (sum p[src]) / cnt + rel_b + r[d] ) ----------------
__global__ __launch_bounds__(256) void k_score(const float* __restrict__ p, const float* __restrict__ r,
                                               const int* __restrict__ csr, const int* __restrict__ off,
                                               const int* __restrict__ deg, const float* __restrict__ relb,
                                               float* __restrict__ score) {
    int d = blockIdx.x * 4 + (threadIdx.x >> 6);
    int lane = threadIdx.x & 63;
    int o = off[d], n = deg[d];
    float a = 0.f;
    for (int j = lane; j < n; j += 64) a += p[csr[o + j]];
    for (int m = 32; m > 0; m >>= 1) a += __shfl_xor(a, m);
    if (lane == 0) {
        float cnt = (float)(n > 0 ? n : 1);
        score[d] = tanhf(a / cnt + relb[0] + r[d]);
    }
}

// ---------------- per-graph exact top-k via radix-select + direct ranking ----------------
__global__ __launch_bounds__(1024) void k_topk(const float* __restrict__ score, const float* __restrict__ h,
                                               float* __restrict__ out) {
    __shared__ u32 ms[NPG];
    __shared__ u32 hist[256];
    __shared__ u32 sbuf[1024];
    __shared__ u64 sel[KOUT];
    __shared__ float ordv[KOUT];
    __shared__ int ordi[KOUT];
    __shared__ u32 selCnt, sPrefix, sNeed, sB;

    int g = blockIdx.x;
    int tid = threadIdx.x;

    for (int i = tid; i < NPG; i += 1024) {
        u32 u = __float_as_uint(score[(size_t)g * NPG + i]);
        ms[i] = (u & 0x80000000u) ? ~u : (u | 0x80000000u);
    }
    if (tid == 0) { sNeed = KOUT; sPrefix = 0; selCnt = 0; }
    __syncthreads();

    for (int pass = 0; pass < 4; pass++) {
        int shift = 24 - pass * 8;
        if (tid < 256) hist[tid] = 0;
        __syncthreads();
        u32 pfx = sPrefix;
        for (int i = tid; i < NPG; i += 1024) {
            u32 v = ms[i];
            if (pass == 0 || (v >> (shift + 8)) == pfx)
                atomicAdd(&hist[(v >> shift) & 255u], 1u);
        }
        __syncthreads();
        if (tid < 256) sbuf[tid] = hist[tid];
        __syncthreads();
        for (int ofs = 1; ofs < 256; ofs <<= 1) {
            u32 t = 0;
            if (tid < 256 && tid + ofs < 256) t = sbuf[tid + ofs];
            __syncthreads();
            if (tid < 256) sbuf[tid] += t;
            __syncthreads();
        }
        u32 need = sNeed;
        if (tid < 256) {
            if (sbuf[tid] >= need && (tid == 255 || sbuf[tid + 1] < need)) sB = (u32)tid;
        }
        __syncthreads();
        if (tid == 0) {
            u32 B = sB;
            u32 above = (B == 255) ? 0u : sbuf[B + 1];
            sNeed = need - above;
            sPrefix = (sPrefix << 8) | B;
        }
        __syncthreads();
    }
    u32 T = sPrefix;
    u32 rTie = sNeed;

    int base = tid * 8;
    u32 lc = 0;
#pragma unroll
    for (int j = 0; j < 8; j++) lc += (ms[base + j] == T);
    __syncthreads();
    sbuf[tid] = lc;
    __syncthreads();
    u32 own = lc;
    for (int ofs = 1; ofs < 1024; ofs <<= 1) {
        u32 t = (tid >= ofs) ? sbuf[tid - ofs] : 0;
        __syncthreads();
        sbuf[tid] += t;
        __syncthreads();
    }
    u32 excl = sbuf[tid] - own;

#pragma unroll
    for (int j = 0; j < 8; j++) {
        int i = base + j;
        u32 v = ms[i];
        bool pick = (v > T) || ((v == T) && (excl < rTie));
        if (v == T) excl++;
        if (pick) {
            u32 slot = atomicAdd(&selCnt, 1u);
            sel[slot] = ((u64)v << 32) | (u32)(NPG - 1 - i);
        }
    }
    __syncthreads();

    if (tid < KOUT) {
        u64 mine = sel[tid];
        int rank = 0;
        for (int j = 0; j < KOUT; j++) rank += (sel[j] > mine);
        u32 v = (u32)(mine >> 32);
        int idx = NPG - 1 - (int)(mine & 0xFFFFFFFFu);
        u32 uu = (v & 0x80000000u) ? (v & 0x7FFFFFFFu) : ~v;
        ordv[rank] = __uint_as_float(uu);
        ordi[rank] = idx;
    }
    __syncthreads();

    for (int t = tid; t < KOUT * 128; t += 1024) {
        int r = t >> 7, c = t & 127;
        int node = g * NPG + ordi[r];
        out[((size_t)g * KOUT + r) * 128 + c] = h[(size_t)node * 128 + c] * ordv[r];
    }
    for (int t = tid; t < KOUT; t += 1024)
        out[(size_t)4 * KOUT * 128 + (size_t)g * KOUT + t] = (float)g;
}

extern "C" void kernel_launch(void* const* d_in, const int* in_sizes, int n_in,
                              void* d_out, int out_size, void* d_ws, size_t ws_size,
                              hipStream_t stream) {
    const float* x        = (const float*)d_in[0];
    const float* mesh_pos = (const float*)d_in[1];
    const int*   edges    = (const int*)d_in[2];
    const float* proj_w   = (const float*)d_in[4];
    const float* proj_b   = (const float*)d_in[5];
    const float* msg_w1   = (const float*)d_in[6];
    const float* msg_b1   = (const float*)d_in[7];
    const float* msg_w2   = (const float*)d_in[8];
    const float* msg_b2   = (const float*)d_in[9];
    const float* upd_w1   = (const float*)d_in[10];
    const float* upd_b1   = (const float*)d_in[11];
    const float* upd_w2   = (const float*)d_in[12];
    const float* upd_b2   = (const float*)d_in[13];
    const float* pool_rel_w  = (const float*)d_in[14];
    const float* pool_rel_b  = (const float*)d_in[15];
    const float* pool_root_w = (const float*)d_in[16];
    float* out = (float*)d_out;

    // workspace: 3 x 16MB node buffers + small arrays (~51.1MB)
    char* w = (char*)d_ws;
    float* h  = (float*)(w);                   // h0 -> h_new (in place)
    float* v  = (float*)(w + (1ull << 24));    // v (dead after accum)
    float* S  = (float*)(w + (2ull << 24));    // u -> S
    char* sm  = w + (3ull << 24);
    int*   deg   = (int*)(sm);
    int*   off   = (int*)(sm + 131072);
    int*   cur   = (int*)(sm + 262144);
    float* rsA   = (float*)(sm + 393216);
    float* bgA   = (float*)(sm + 524288);
    float* pp    = (float*)(sm + 655360);
    float* rr    = (float*)(sm + 786432);
    float* score = (float*)(sm + 917504);
    int*   csr   = (int*)(sm + 1048576);       // 2MB

    k_h0<<<N_NODESC / 2, 256, 0, stream>>>(x, mesh_pos, proj_w, proj_b, h, deg);
    k_deg<<<N_EDGESC / 256, 256, 0, stream>>>(edges, deg);
    k_scan<<<1, 1024, 0, stream>>>(deg, off, cur, rsA, bgA);
    k_fill<<<N_EDGESC / 256, 256, 0, stream>>>(edges, cur, csr);
    k_sortcsr<<<N_NODESC / 4, 256, 0, stream>>>(csr, off, deg);

    // v = h@W1b ; S = h@W1a + b1   (one pass over h)
    gemm_dualw<<<1024, 256, 0, stream>>>(h, msg_w1 + 128 * 128, msg_w1, msg_b1, v, S);
    // S[d] = sum_e silu( S[d] + v[src_e] )   (in place)
    k_accum_S<<<N_NODESC / 4, 256, 0, stream>>>(v, csr, off, deg, S);
    // fused: agg = (S@W2)*rs + b2*bg ; q = silu(h@U1a + agg@U1b + ub1) ;
    //        h = h + q@U2 + ub2 ; p/r dots
    gemm_chain<<<1024, 256, 0, stream>>>(S, h, msg_w2, msg_b2, rsA, bgA,
                                         upd_w1, upd_w1 + 128 * 128, upd_b1,
                                         upd_w2, upd_b2,
                                         pool_rel_w, pool_root_w, pp, rr);

    k_score<<<N_NODESC / 4, 256, 0, stream>>>(pp, rr, csr, off, deg, pool_rel_b, score);
    k_topk<<<4, 1024, 0, stream>>>(score, h, out);
}

// Round 15
// 374.635 us; speedup vs baseline: 24.6120x; 1.0319x over previous
//
#include <hip/hip_runtime.h>
#include <hip/hip_bf16.h>
#include <math.h>

#define N_NODESC 32768
#define N_EDGESC 524288
#define NPG 8192
#define KOUT 512

typedef unsigned short u16;
typedef unsigned int u32;
typedef unsigned long long u64;

__device__ __forceinline__ float siluf(float x) {
    return x / (1.f + __expf(-x));
}

// ---------------- h0 = x@proj_w + proj_b + sincos(mesh_pos)  (+ zero deg) ----------------
__global__ __launch_bounds__(256) void k_h0(const float* __restrict__ x,
                                            const float* __restrict__ pos,
                                            const float* __restrict__ pw,
                                            const float* __restrict__ pb,
                                            float* __restrict__ h,
                                            int* __restrict__ deg) {
    int gid = blockIdx.x * 256 + threadIdx.x;
    if (gid < N_NODESC) deg[gid] = 0;
    int node = blockIdx.x * 2 + (threadIdx.x >> 7);
    int c = threadIdx.x & 127;
    float x0 = x[node * 3 + 0];
    float x1 = x[node * 3 + 1];
    float x2 = x[node * 3 + 2];
    float acc = x0 * pw[c] + x1 * pw[128 + c] + x2 * pw[256 + c];
    acc += pb[c];
    int dim = c >> 6;
    int inner = c & 63;
    int jj = inner & 31;
    float p = pos[node * 2 + dim];
    float omega = exp2f(-(float)jj * 0.41524101186092027f);
    float ang = p * omega;
    acc += (inner < 32) ? __sinf(ang) : __cosf(ang);
    h[(size_t)node * 128 + c] = acc;
}

// ---------------- degree histogram ----------------
__global__ __launch_bounds__(256) void k_deg(const int* __restrict__ edges, int* __restrict__ deg) {
    int e = blockIdx.x * 256 + threadIdx.x;
    if (e < N_EDGESC) {
        int2 e2 = ((const int2*)edges)[e];
        atomicAdd(&deg[e2.y], 1);
    }
}

// ---------------- exclusive scan (32768 = 1024 threads x 32) ----------------
__global__ __launch_bounds__(1024) void k_scan(const int* __restrict__ deg,
                                               int* __restrict__ off, int* __restrict__ cur,
                                               float* __restrict__ rs, float* __restrict__ bg) {
    __shared__ int ls[1024];
    int tid = threadIdx.x;
    int base = tid * 32;
    int v[32];
    int s = 0;
#pragma unroll
    for (int j = 0; j < 32; j++) { v[j] = deg[base + j]; s += v[j]; }
    ls[tid] = s;
    __syncthreads();
    for (int ofs = 1; ofs < 1024; ofs <<= 1) {
        int t = (tid >= ofs) ? ls[tid - ofs] : 0;
        __syncthreads();
        ls[tid] += t;
        __syncthreads();
    }
    int run = ls[tid] - s;
#pragma unroll
    for (int j = 0; j < 32; j++) {
        off[base + j] = run;
        cur[base + j] = run;
        int d = v[j];
        rs[base + j] = 1.f / (float)(d > 0 ? d : 1);
        bg[base + j] = d > 0 ? 1.f : 0.f;
        run += d;
    }
}

// ---------------- CSR fill (placement order nondeterministic; sorted next) ----------------
__global__ __launch_bounds__(256) void k_fill(const int* __restrict__ edges,
                                              int* __restrict__ cur, int* __restrict__ csr) {
    int e = blockIdx.x * 256 + threadIdx.x;
    if (e < N_EDGESC) {
        int2 e2 = ((const int2*)edges)[e];
        int pos = atomicAdd(&cur[e2.y], 1);
        csr[pos] = e2.x;
    }
}

// ---------------- canonicalize CSR: sort each segment ascending by src ----------------
__global__ __launch_bounds__(256) void k_sortcsr(int* __restrict__ csr,
                                                 const int* __restrict__ off,
                                                 const int* __restrict__ deg) {
    int d = blockIdx.x * 4 + (threadIdx.x >> 6);
    int lane = threadIdx.x & 63;
    int o = off[d], n = deg[d];
    if (n <= 1) return;
    if (n <= 64) {
        int key = (lane < n) ? csr[o + lane] : 0x7FFFFFFF;
        for (int k = 2; k <= 64; k <<= 1) {
            for (int j = k >> 1; j > 0; j >>= 1) {
                int partner = __shfl_xor(key, j);
                bool asc = ((lane & k) == 0);
                bool keepMin = (((lane & j) == 0) == asc);
                key = keepMin ? min(key, partner) : max(key, partner);
            }
        }
        if (lane < n) csr[o + lane] = key;
    } else {
        if (lane == 0) {
            for (int i = o + 1; i < o + n; i++) {
                int x = csr[i];
                int j = i - 1;
                while (j >= o && csr[j] > x) { csr[j + 1] = csr[j]; j--; }
                csr[j + 1] = x;
            }
        }
    }
}

// ---------------- dual-W GEMM: V = A@Wv ; U = A@Wu + bu  (double-buffered W) ----------------
// 16-row W chunks, ping-pong staged (stage c+1 while computing c): 1 barrier/chunk.
// k ascending per accumulator -> bitwise identical to r14.
__global__ __launch_bounds__(256, 2) void gemm_dualw(const float* __restrict__ A,
                                                     const float* __restrict__ Wv,
                                                     const float* __restrict__ Wu,
                                                     const float* __restrict__ bu,
                                                     float* __restrict__ V, float* __restrict__ U) {
    __shared__ float Wsv[2][16 * 128];   // 2 x 8KB
    __shared__ float Wsu[2][16 * 128];   // 2 x 8KB
    int tid = threadIdx.x;
    int cg = tid & 31;
    int rg = tid >> 5;
    int m0 = blockIdx.x * 32 + rg * 4;
    int c0 = cg * 4;
    const float* Ar = A + (size_t)m0 * 128;

    float accv[4][4], accu[4][4];
#pragma unroll
    for (int r = 0; r < 4; r++)
#pragma unroll
        for (int c = 0; c < 4; c++) { accv[r][c] = 0.f; accu[r][c] = 0.f; }

#define STAGE_DW(buf, kc)                                                          \
    {                                                                              \
        const float4* Wgv = (const float4*)(Wv + (size_t)(kc) * 128);              \
        const float4* Wgu = (const float4*)(Wu + (size_t)(kc) * 128);              \
        float4* Wlv = (float4*)Wsv[buf];                                           \
        float4* Wlu = (float4*)Wsu[buf];                                           \
        _Pragma("unroll") for (int i = 0; i < 2; i++) {                            \
            Wlv[tid + i * 256] = Wgv[tid + i * 256];                               \
            Wlu[tid + i * 256] = Wgu[tid + i * 256];                               \
        }                                                                          \
    }

    STAGE_DW(0, 0)
    __syncthreads();
    for (int c = 0; c < 8; c++) {
        int buf = c & 1;
        if (c + 1 < 8) STAGE_DW(buf ^ 1, (c + 1) * 16)
        int kc = c * 16;
#pragma unroll
        for (int k0 = 0; k0 < 16; k0 += 4) {
            float4 a[4];
#pragma unroll
            for (int r = 0; r < 4; r++) a[r] = *(const float4*)(Ar + r * 128 + kc + k0);
#pragma unroll
            for (int kk = 0; kk < 4; kk++) {
                float4 wv = *(const float4*)(Wsv[buf] + (k0 + kk) * 128 + c0);
                float4 wu = *(const float4*)(Wsu[buf] + (k0 + kk) * 128 + c0);
#pragma unroll
                for (int r = 0; r < 4; r++) {
                    float aa = ((const float*)&a[r])[kk];
                    accv[r][0] += aa * wv.x; accv[r][1] += aa * wv.y;
                    accv[r][2] += aa * wv.z; accv[r][3] += aa * wv.w;
                    accu[r][0] += aa * wu.x; accu[r][1] += aa * wu.y;
                    accu[r][2] += aa * wu.z; accu[r][3] += aa * wu.w;
                }
            }
        }
        __syncthreads();
    }
#undef STAGE_DW
#pragma unroll
    for (int r = 0; r < 4; r++) {
        int row = m0 + r;
        float4 ov, ou;
        ov.x = accv[r][0]; ov.y = accv[r][1]; ov.z = accv[r][2]; ov.w = accv[r][3];
        ou.x = accu[r][0] + bu[c0];
        ou.y = accu[r][1] + bu[c0 + 1];
        ou.z = accu[r][2] + bu[c0 + 2];
        ou.w = accu[r][3] + bu[c0 + 3];
        *(float4*)(V + (size_t)row * 128 + c0) = ov;
        *(float4*)(U + (size_t)row * 128 + c0) = ou;
    }
}

// ---------------- fused post-accum chain, double-buffered W ----------------
// stage1: aggT = (S@W2)*rs + b2*bg ; stage2: q = silu(h@U1a + aggT@U1b + ub1) ;
// stage3: h = h + qT@U2 + ub2 + p/r dots. W chunks (32 rows) ping-pong staged:
// stage c+1 issued before compute c -> global-W latency hidden; 1 barrier/chunk.
// FMA order per accumulator k-ascending; epilogues copied from r14 -> bit-identical.
__global__ __launch_bounds__(256, 2) void gemm_chain(const float* __restrict__ S,
                                                     float* __restrict__ h,
                                                     const float* __restrict__ W2,
                                                     const float* __restrict__ b2,
                                                     const float* __restrict__ rs,
                                                     const float* __restrict__ bg,
                                                     const float* __restrict__ U1a,
                                                     const float* __restrict__ U1b,
                                                     const float* __restrict__ ub1,
                                                     const float* __restrict__ U2,
                                                     const float* __restrict__ ub2,
                                                     const float* __restrict__ wrel,
                                                     const float* __restrict__ wroot,
                                                     float* __restrict__ pout,
                                                     float* __restrict__ rout) {
    __shared__ float Wc[2][32 * 128];   // 2 x 16KB rotating weight chunks
    __shared__ float T[32 * 128];       // 16KB tile: agg, then q
    int tid = threadIdx.x;
    int cg = tid & 31;
    int rg = tid >> 5;
    int m0 = blockIdx.x * 32 + rg * 4;
    int c0 = cg * 4;
    const float* Sr = S + (size_t)m0 * 128;
    const float* hr = h + (size_t)m0 * 128;

    float acc1[4][4], acc2[4][4];

#define ZERO(acc)                                                          \
    {                                                                      \
        _Pragma("unroll") for (int r = 0; r < 4; r++)                      \
            _Pragma("unroll") for (int c = 0; c < 4; c++) acc[r][c] = 0.f; \
    }
#define STAGE_W(buf, Wsrc, kc)                                             \
    {                                                                      \
        const float4* Wg = (const float4*)((Wsrc) + (size_t)(kc) * 128);   \
        float4* Wl = (float4*)Wc[buf];                                     \
        _Pragma("unroll") for (int i = 0; i < 4; i++)                      \
            Wl[tid + i * 256] = Wg[tid + i * 256];                         \
    }
#define COMPUTE_G(acc, buf, Abase, kc)                                     \
    {                                                                      \
        _Pragma("unroll") for (int k0 = 0; k0 < 32; k0 += 4) {             \
            float4 a[4];                                                   \
            _Pragma("unroll") for (int r = 0; r < 4; r++)                  \
                a[r] = *(const float4*)((Abase) + r * 128 + (kc) + k0);    \
            _Pragma("unroll") for (int kk = 0; kk < 4; kk++) {             \
                float4 wv = *(const float4*)(Wc[buf] + (k0 + kk) * 128 + c0); \
                _Pragma("unroll") for (int r = 0; r < 4; r++) {            \
                    float aa = ((const float*)&a[r])[kk];                  \
                    acc[r][0] += aa * wv.x; acc[r][1] += aa * wv.y;        \
                    acc[r][2] += aa * wv.z; acc[r][3] += aa * wv.w;        \
                }                                                          \
            }                                                              \
        }                                                                  \
    }
#define COMPUTE_T(acc, buf, kc)                                            \
    {                                                                      \
        _Pragma("unroll") for (int k0 = 0; k0 < 32; k0 += 4) {             \
            float4 a[4];                                                   \
            _Pragma("unroll") for (int r = 0; r < 4; r++)                  \
                a[r] = *(const float4*)(T + (rg * 4 + r) * 128 + (kc) + k0); \
            _Pragma("unroll") for (int kk = 0; kk < 4; kk++) {             \
                float4 wv = *(const float4*)(Wc[buf] + (k0 + kk) * 128 + c0); \
                _Pragma("unroll") for (int r = 0; r < 4; r++) {            \
                    float aa = ((const float*)&a[r])[kk];                  \
                    acc[r][0] += aa * wv.x; acc[r][1] += aa * wv.y;        \
                    acc[r][2] += aa * wv.z; acc[r][3] += aa * wv.w;        \
                }                                                          \
            }                                                              \
        }                                                                  \
    }
// double-buffered GEMM pass over a global A source
#define PASS_G(acc, Wsrc, Abase)                                           \
    {                                                                      \
        STAGE_W(0, Wsrc, 0)                                                \
        __syncthreads();                                                   \
        _Pragma("unroll") for (int c = 0; c < 4; c++) {                    \
            int buf = c & 1;                                               \
            if (c + 1 < 4) STAGE_W(buf ^ 1, Wsrc, (c + 1) * 32)            \
            COMPUTE_G(acc, buf, Abase, c * 32)                             \
            __syncthreads();                                               \
        }                                                                  \
    }
#define PASS_T(acc, Wsrc)                                                  \
    {                                                                      \
        STAGE_W(0, Wsrc, 0)                                                \
        __syncthreads();                                                   \
        _Pragma("unroll") for (int c = 0; c < 4; c++) {                    \
            int buf = c & 1;                                               \
            if (c + 1 < 4) STAGE_W(buf ^ 1, Wsrc, (c + 1) * 32)            \
            COMPUTE_T(acc, buf, c * 32)                                    \
            __syncthreads();                                               \
        }                                                                  \
    }

    // ---- stage 1: acc1 = S@W2 ; aggT = acc1*rs + b2*bg ----
    ZERO(acc1)
    PASS_G(acc1, W2, Sr)
#pragma unroll
    for (int r = 0; r < 4; r++) {
        int row = m0 + r;
        float rsv = rs[row];
        float bgv = bg[row];
        float4 o;
        float* op = (float*)&o;
#pragma unroll
        for (int c = 0; c < 4; c++) {
            float xv = acc1[r][c];
            xv *= rsv;
            xv += b2[c0 + c] * bgv;
            op[c] = xv;
        }
        *(float4*)(T + (rg * 4 + r) * 128 + c0) = o;
    }
    __syncthreads();   // aggT visible

    // ---- stage 2: acc1 = h@U1a ; acc2 = aggT@U1b ; q = silu(acc1+acc2+ub1) ----
    ZERO(acc1)
    PASS_G(acc1, U1a, hr)
    ZERO(acc2)
    PASS_T(acc2, U1b)
    __syncthreads();   // all reads of aggT done before overwrite
#pragma unroll
    for (int r = 0; r < 4; r++) {
        float4 o;
        float* op = (float*)&o;
#pragma unroll
        for (int c = 0; c < 4; c++) {
            float xv = acc1[r][c];
            xv += acc2[r][c];
            xv += ub1[c0 + c];
            op[c] = siluf(xv);
        }
        *(float4*)(T + (rg * 4 + r) * 128 + c0) = o;
    }
    __syncthreads();   // qT visible

    // ---- stage 3: acc1 = qT@U2 ; h = acc1 + ub2 + h ; p/r dots ----
    ZERO(acc1)
    PASS_T(acc1, U2)
    float prel[4], prot[4];
#pragma unroll
    for (int r = 0; r < 4; r++) {
        int row = m0 + r;
        float4 o;
        float* op = (float*)&o;
#pragma unroll
        for (int c = 0; c < 4; c++) {
            float xv = acc1[r][c];
            xv *= 1.f;
            xv += ub2[c0 + c] * 1.f;
            xv += hr[r * 128 + c0 + c];
            op[c] = xv;
        }
        prel[r] = op[0] * wrel[c0] + op[1] * wrel[c0 + 1] + op[2] * wrel[c0 + 2] + op[3] * wrel[c0 + 3];
        prot[r] = op[0] * wroot[c0] + op[1] * wroot[c0 + 1] + op[2] * wroot[c0 + 2] + op[3] * wroot[c0 + 3];
        *(float4*)(h + (size_t)row * 128 + c0) = o;
    }
#pragma unroll
    for (int r = 0; r < 4; r++) {
        float a = prel[r], b = prot[r];
#pragma unroll
        for (int m = 1; m < 32; m <<= 1) {
            a += __shfl_xor(a, m);
            b += __shfl_xor(b, m);
        }
        if (cg == 0) { pout[m0 + r] = a; rout[m0 + r] = b; }
    }
#undef ZERO
#undef STAGE_W
#undef COMPUTE_G
#undef COMPUTE_T
#undef PASS_G
#undef PASS_T
}

// ---------------- S[d] = sum_{e:dst=d} silu(u[d] + v[src_e]) ; wave per node ----------------
// r12 batch-8 scalar gather (proven 48.6 µs; S bit pattern passed in r12).
__global__ __launch_bounds__(256) void k_accum_S(const float* __restrict__ v,
                                                 const int* __restrict__ csr, const int* __restrict__ off,
                                                 const int* __restrict__ deg, float* S) {
    int d = blockIdx.x * 4 + (threadIdx.x >> 6);
    int lane = threadIdx.x & 63;
    float* srow = S + (size_t)d * 128;
    float u0 = srow[lane];
    float u1 = srow[64 + lane];
    float a0 = 0.f, a1 = 0.f;
    int o = off[d], n = deg[d];
    for (int base = 0; base < n; base += 64) {
        int cnt = min(64, n - base);
        int sall = (lane < cnt) ? csr[o + base + lane] : 0;
        int j = 0;
        for (; j + 8 <= cnt; j += 8) {
            int s0 = __shfl(sall, j + 0), s1 = __shfl(sall, j + 1);
            int s2 = __shfl(sall, j + 2), s3 = __shfl(sall, j + 3);
            int s4 = __shfl(sall, j + 4), s5 = __shfl(sall, j + 5);
            int s6 = __shfl(sall, j + 6), s7 = __shfl(sall, j + 7);
            float v00 = v[(size_t)s0 * 128 + lane], v01 = v[(size_t)s0 * 128 + 64 + lane];
            float v10 = v[(size_t)s1 * 128 + lane], v11 = v[(size_t)s1 * 128 + 64 + lane];
            float v20 = v[(size_t)s2 * 128 + lane], v21 = v[(size_t)s2 * 128 + 64 + lane];
            float v30 = v[(size_t)s3 * 128 + lane], v31 = v[(size_t)s3 * 128 + 64 + lane];
            float v40 = v[(size_t)s4 * 128 + lane], v41 = v[(size_t)s4 * 128 + 64 + lane];
            float v50 = v[(size_t)s5 * 128 + lane], v51 = v[(size_t)s5 * 128 + 64 + lane];
            float v60 = v[(size_t)s6 * 128 + lane], v61 = v[(size_t)s6 * 128 + 64 + lane];
            float v70 = v[(size_t)s7 * 128 + lane], v71 = v[(size_t)s7 * 128 + 64 + lane];
            a0 += siluf(u0 + v00); a1 += siluf(u1 + v01);
            a0 += siluf(u0 + v10); a1 += siluf(u1 + v11);
            a0 += siluf(u0 + v20); a1 += siluf(u1 + v21);
            a0 += siluf(u0 + v30); a1 += siluf(u1 + v31);
            a0 += siluf(u0 + v40); a1 += siluf(u1 + v41);
            a0 += siluf(u0 + v50); a1 += siluf(u1 + v51);
            a0 += siluf(u0 + v60); a1 += siluf(u1 + v61);
            a0 += siluf(u0 + v70); a1 += siluf(u1 + v71);
        }
        for (; j < cnt; j++) {
            int s = __shfl(sall, j);
            a0 += siluf(u0 + v[(size_t)s * 128 + lane]);
            a1 += siluf(u1 + v[(size_t)s * 128 + 64 + lane]);
        }
    }
    srow[lane] = a0;
    srow[64 + lane] = a1;
}

// ---------------- score[d] = tanh( (sum p[src]) / cnt + rel_b + r[d] ) ----------------
__global__ __launch_bounds__(256) void k_score(const float* __restrict__ p, const float* __restrict__ r,
                                               const int* __restrict__ csr, const int* __restrict__ off,
                                               const int* __restrict__ deg, const float* __restrict__ relb,
                                               float* __restrict__ score) {
    int d = blockIdx.x * 4 + (threadIdx.x >> 6);
    int lane = threadIdx.x & 63;
    int o = off[d], n = deg[d];
    float a = 0.f;
    for (int j = lane; j < n; j += 64) a += p[csr[o + j]];
    for (int m = 32; m > 0; m >>= 1) a += __shfl_xor(a, m);
    if (lane == 0) {
        float cnt = (float)(n > 0 ? n : 1);
        score[d] = tanhf(a / cnt + relb[0] + r[d]);
    }
}

// ---------------- per-graph exact top-k via radix-select + direct ranking ----------------
__global__ __launch_bounds__(1024) void k_topk(const float* __restrict__ score, const float* __restrict__ h,
                                               float* __restrict__ out) {
    __shared__ u32 ms[NPG];
    __shared__ u32 hist[256];
    __shared__ u32 sbuf[1024];
    __shared__ u64 sel[KOUT];
    __shared__ float ordv[KOUT];
    __shared__ int ordi[KOUT];
    __shared__ u32 selCnt, sPrefix, sNeed, sB;

    int g = blockIdx.x;
    int tid = threadIdx.x;

    for (int i = tid; i < NPG; i += 1024) {
        u32 u = __float_as_uint(score[(size_t)g * NPG + i]);
        ms[i] = (u & 0x80000000u) ? ~u : (u | 0x80000000u);
    }
    if (tid == 0) { sNeed = KOUT; sPrefix = 0; selCnt = 0; }
    __syncthreads();

    for (int pass = 0; pass < 4; pass++) {
        int shift = 24 - pass * 8;
        if (tid < 256) hist[tid] = 0;
        __syncthreads();
        u32 pfx = sPrefix;
        for (int i = tid; i < NPG; i += 1024) {
            u32 v = ms[i];
            if (pass == 0 || (v >> (shift + 8)) == pfx)
                atomicAdd(&hist[(v >> shift) & 255u], 1u);
        }
        __syncthreads();
        if (tid < 256) sbuf[tid] = hist[tid];
        __syncthreads();
        for (int ofs = 1; ofs < 256; ofs <<= 1) {
            u32 t = 0;
            if (tid < 256 && tid + ofs < 256) t = sbuf[tid + ofs];
            __syncthreads();
            if (tid < 256) sbuf[tid] += t;
            __syncthreads();
        }
        u32 need = sNeed;
        if (tid < 256) {
            if (sbuf[tid] >= need && (tid == 255 || sbuf[tid + 1] < need)) sB = (u32)tid;
        }
        __syncthreads();
        if (tid == 0) {
            u32 B = sB;
            u32 above = (B == 255) ? 0u : sbuf[B + 1];
            sNeed = need - above;
            sPrefix = (sPrefix << 8) | B;
        }
        __syncthreads();
    }
    u32 T = sPrefix;
    u32 rTie = sNeed;

    int base = tid * 8;
    u32 lc = 0;
#pragma unroll
    for (int j = 0; j < 8; j++) lc += (ms[base + j] == T);
    __syncthreads();
    sbuf[tid] = lc;
    __syncthreads();
    u32 own = lc;
    for (int ofs = 1; ofs < 1024; ofs <<= 1) {
        u32 t = (tid >= ofs) ? sbuf[tid - ofs] : 0;
        __syncthreads();
        sbuf[tid] += t;
        __syncthreads();
    }
    u32 excl = sbuf[tid] - own;

#pragma unroll
    for (int j = 0; j < 8; j++) {
        int i = base + j;
        u32 v = ms[i];
        bool pick = (v > T) || ((v == T) && (excl < rTie));
        if (v == T) excl++;
        if (pick) {
            u32 slot = atomicAdd(&selCnt, 1u);
            sel[slot] = ((u64)v << 32) | (u32)(NPG - 1 - i);
        }
    }
    __syncthreads();

    if (tid < KOUT) {
        u64 mine = sel[tid];
        int rank = 0;
        for (int j = 0; j < KOUT; j++) rank += (sel[j] > mine);
        u32 v = (u32)(mine >> 32);
        int idx = NPG - 1 - (int)(mine & 0xFFFFFFFFu);
        u32 uu = (v & 0x80000000u) ? (v & 0x7FFFFFFFu) : ~v;
        ordv[rank] = __uint_as_float(uu);
        ordi[rank] = idx;
    }
    __syncthreads();

    for (int t = tid; t < KOUT * 128; t += 1024) {
        int r = t >> 7, c = t & 127;
        int node = g * NPG + ordi[r];
        out[((size_t)g * KOUT + r) * 128 + c] = h[(size_t)node * 128 + c] * ordv[r];
    }
    for (int t = tid; t < KOUT; t += 1024)
        out[(size_t)4 * KOUT * 128 + (size_t)g * KOUT + t] = (float)g;
}

extern "C" void kernel_launch(void* const* d_in, const int* in_sizes, int n_in,
                              void* d_out, int out_size, void* d_ws, size_t ws_size,
                              hipStream_t stream) {
    const float* x        = (const float*)d_in[0];
    const float* mesh_pos = (const float*)d_in[1];
    const int*   edges    = (const int*)d_in[2];
    const float* proj_w   = (const float*)d_in[4];
    const float* proj_b   = (const float*)d_in[5];
    const float* msg_w1   = (const float*)d_in[6];
    const float* msg_b1   = (const float*)d_in[7];
    const float* msg_w2   = (const float*)d_in[8];
    const float* msg_b2   = (const float*)d_in[9];
    const float* upd_w1   = (const float*)d_in[10];
    const float* upd_b1   = (const float*)d_in[11];
    const float* upd_w2   = (const float*)d_in[12];
    const float* upd_b2   = (const float*)d_in[13];
    const float* pool_rel_w  = (const float*)d_in[14];
    const float* pool_rel_b  = (const float*)d_in[15];
    const float* pool_root_w = (const float*)d_in[16];
    float* out = (float*)d_out;

    // workspace: 3 x 16MB node buffers + small arrays (~51.1MB)
    char* w = (char*)d_ws;
    float* h  = (float*)(w);                   // h0 -> h_new (in place)
    float* v  = (float*)(w + (1ull << 24));    // v (dead after accum)
    float* S  = (float*)(w + (2ull << 24));    // u -> S
    char* sm  = w + (3ull << 24);
    int*   deg   = (int*)(sm);
    int*   off   = (int*)(sm + 131072);
    int*   cur   = (int*)(sm + 262144);
    float* rsA   = (float*)(sm + 393216);
    float* bgA   = (float*)(sm + 524288);
    float* pp    = (float*)(sm + 655360);
    float* rr    = (float*)(sm + 786432);
    float* score = (float*)(sm + 917504);
    int*   csr   = (int*)(sm + 1048576);       // 2MB

    k_h0<<<N_NODESC / 2, 256, 0, stream>>>(x, mesh_pos, proj_w, proj_b, h, deg);
    k_deg<<<N_EDGESC / 256, 256, 0, stream>>>(edges, deg);
    k_scan<<<1, 1024, 0, stream>>>(deg, off, cur, rsA, bgA);
    k_fill<<<N_EDGESC / 256, 256, 0, stream>>>(edges, cur, csr);
    k_sortcsr<<<N_NODESC / 4, 256, 0, stream>>>(csr, off, deg);

    // v = h@W1b ; S = h@W1a + b1   (one pass over h)
    gemm_dualw<<<1024, 256, 0, stream>>>(h, msg_w1 + 128 * 128, msg_w1, msg_b1, v, S);
    // S[d] = sum_e silu( S[d] + v[src_e] )   (in place)
    k_accum_S<<<N_NODESC / 4, 256, 0, stream>>>(v, csr, off, deg, S);
    // fused: agg = (S@W2)*rs + b2*bg ; q = silu(h@U1a + agg@U1b + ub1) ;
    //        h = h + q@U2 + ub2 ; p/r dots
    gemm_chain<<<1024, 256, 0, stream>>>(S, h, msg_w2, msg_b2, rsA, bgA,
                                         upd_w1, upd_w1 + 128 * 128, upd_b1,
                                         upd_w2, upd_b2,
                                         pool_rel_w, pool_root_w, pp, rr);

    k_score<<<N_NODESC / 4, 256, 0, stream>>>(pp, rr, csr, off, deg, pool_rel_b, score);
    k_topk<<<4, 1024, 0, stream>>>(score, h, out);
}